// Round 12
// baseline (843.620 us; speedup 1.0000x reference)
//
#include <hip/hip_runtime.h>
#include <stdint.h>

#define TPB 128
typedef unsigned short u16;
typedef unsigned int u32;
using short8 = __attribute__((ext_vector_type(8))) short;
using f32x16 = __attribute__((ext_vector_type(16))) float;

__device__ __forceinline__ float sigf(float x){
  return __builtin_amdgcn_rcpf(1.0f + __expf(-x));
}
__device__ __forceinline__ float tanh_f(float x){
  return 1.0f - 2.0f*__builtin_amdgcn_rcpf(1.0f + __expf(2.0f*x));
}
__device__ __forceinline__ u16 f2bf(float f){
  u32 u = __float_as_uint(f);
  u += 0x7FFFu + ((u>>16)&1u);
  return (u16)(u>>16);
}
__device__ __forceinline__ float bf2f(u16 h){ return __uint_as_float(((u32)h)<<16); }

// ---------------- CSR build ----------------
__global__ void k_deg(const int* __restrict__ dst, int* __restrict__ deg, int E){
  int i = blockIdx.x*256 + threadIdx.x;
  if (i < E) atomicAdd(&deg[dst[i]], 1);
}

__global__ __launch_bounds__(256) void k_scan1(const int* __restrict__ deg, int* __restrict__ indptr,
                                               int* __restrict__ bsum, int N){
  __shared__ int s[256];
  int tid = threadIdx.x;
  int i = blockIdx.x*256 + tid;
  int v = (i < N) ? deg[i] : 0;
  s[tid] = v; __syncthreads();
  for (int off=1; off<256; off<<=1){
    int t = (tid>=off) ? s[tid-off] : 0;
    __syncthreads();
    s[tid] += t;
    __syncthreads();
  }
  if (i < N) indptr[i] = s[tid] - v;
  if (tid == 255) bsum[blockIdx.x] = s[255];
}

__global__ __launch_bounds__(512) void k_scan2(const int* __restrict__ bsum, int* __restrict__ boffs,
                                               int* __restrict__ indptr, int nb, int N){
  __shared__ int s[512];
  int tid = threadIdx.x;
  int v = (tid < nb) ? bsum[tid] : 0;
  s[tid] = v; __syncthreads();
  for (int off=1; off<512; off<<=1){
    int t = (tid>=off) ? s[tid-off] : 0;
    __syncthreads();
    s[tid] += t;
    __syncthreads();
  }
  boffs[tid] = s[tid] - v;
  if (tid == nb-1) indptr[N] = s[tid];
}

__global__ __launch_bounds__(256) void k_scan3(int* __restrict__ indptr, const int* __restrict__ boffs, int N){
  int i = blockIdx.x*256 + threadIdx.x;
  if (i < N) indptr[i] += boffs[blockIdx.x];
}

__global__ void k_fill(const int* __restrict__ src, const int* __restrict__ dst,
                       const int* __restrict__ indptr, int* __restrict__ fill,
                       int* __restrict__ col, int E){
  int i = blockIdx.x*256 + threadIdx.x;
  if (i < E){
    int d = dst[i];
    int r = atomicAdd(&fill[d], 1);
    col[indptr[d] + r] = src[i];
  }
}

// ---------------- aggregation v2: one node per wave, edge-slot parallel ----------------
// z[n] = relu( y[n] + sum_{nbr} y[src] + bias ).  Wave = 4 edge-slots x 16 feature-quads.
// Per-wave work = sum(deg)/4 (mean, not max): no per-node tail imbalance inside the wave.
__global__ __launch_bounds__(256) void k_agg2(const float* __restrict__ y, const int* __restrict__ indptr,
                                              const int* __restrict__ col, const float* __restrict__ bias,
                                              float* __restrict__ z, int N){
  const int gwave = (blockIdx.x*256 + threadIdx.x) >> 6;
  const int lane = threadIdx.x & 63;
  const int es = lane >> 4;
  const int fq = lane & 15;
  const float4* hv = (const float4*)y;
  const float4 b4 = ((const float4*)bias)[fq];
  const int n0 = gwave * 8;
  for (int i = 0; i < 8; ++i){
    int n = n0 + i;
    if (n >= N) return;
    int s = indptr[n], e = indptr[n+1];
    float4 acc = make_float4(0.f,0.f,0.f,0.f);
    int p = s + es;
    for (; p + 4 < e; p += 8){
      int c0 = col[p], c1 = col[p+4];
      float4 x0 = hv[(size_t)c0*16 + fq];
      float4 x1 = hv[(size_t)c1*16 + fq];
      acc.x += x0.x + x1.x; acc.y += x0.y + x1.y;
      acc.z += x0.z + x1.z; acc.w += x0.w + x1.w;
    }
    if (p < e){
      float4 x0 = hv[(size_t)col[p]*16 + fq];
      acc.x += x0.x; acc.y += x0.y; acc.z += x0.z; acc.w += x0.w;
    }
    acc.x += __shfl_xor(acc.x, 16); acc.x += __shfl_xor(acc.x, 32);
    acc.y += __shfl_xor(acc.y, 16); acc.y += __shfl_xor(acc.y, 32);
    acc.z += __shfl_xor(acc.z, 16); acc.z += __shfl_xor(acc.z, 32);
    acc.w += __shfl_xor(acc.w, 16); acc.w += __shfl_xor(acc.w, 32);
    if (es == 0){
      float4 sf = hv[(size_t)n*16 + fq];
      float4 o;
      o.x = fmaxf(acc.x + sf.x + b4.x, 0.f);
      o.y = fmaxf(acc.y + sf.y + b4.y, 0.f);
      o.z = fmaxf(acc.z + sf.z + b4.z, 0.f);
      o.w = fmaxf(acc.w + sf.w + b4.w, 0.f);
      ((float4*)z)[(size_t)n*16 + fq] = o;
    }
  }
}

// ---------------- generic f32 GEMM ----------------
__global__ __launch_bounds__(TPB) void k_gemm(const float* __restrict__ A, const float* __restrict__ W,
                                              const float* __restrict__ bias, float* __restrict__ out,
                                              int K, int JC, int act, int N){
  extern __shared__ float sm[];
  float* As = sm;
  float* Ws = sm + (size_t)K*68;
  const int tid = threadIdx.x;
  const int tx = tid & 15, ty = tid >> 4;
  const int nb = blockIdx.x * 64;
  const int kq = K >> 2;
  for (int it = 0, idx = tid; it < (kq >> 1); ++it, idx += TPB){
    int nl = idx & 63, kk = idx >> 6;
    int k4 = kk << 2;
    int n = nb + nl;
    float4 v = make_float4(0.f,0.f,0.f,0.f);
    if (n < N) v = *(const float4*)(A + (size_t)n*K + k4);
    As[(size_t)(k4+0)*68 + nl] = v.x;
    As[(size_t)(k4+1)*68 + nl] = v.y;
    As[(size_t)(k4+2)*68 + nl] = v.z;
    As[(size_t)(k4+3)*68 + nl] = v.w;
  }
  const int ncc = JC >> 5;
  for (int cc = 0; cc < ncc; ++cc){
    __syncthreads();
    for (int it = 0, idx = tid; it < (kq >> 2); ++it, idx += TPB){
      int cl = idx & 31, kk = idx >> 5;
      int k4 = kk << 2;
      int j = (cc << 5) + cl;
      float4 v = *(const float4*)(W + (size_t)j*K + k4);
      Ws[(size_t)(k4+0)*34 + cl] = v.x;
      Ws[(size_t)(k4+1)*34 + cl] = v.y;
      Ws[(size_t)(k4+2)*34 + cl] = v.z;
      Ws[(size_t)(k4+3)*34 + cl] = v.w;
    }
    __syncthreads();
    float4 acc0 = make_float4(0,0,0,0), acc1 = acc0, acc2 = acc0, acc3 = acc0;
    #pragma unroll 4
    for (int k = 0; k < K; ++k){
      float4 a = *(const float4*)(As + (size_t)k*68 + (tx<<2));
      float2 w01 = *(const float2*)(Ws + (size_t)k*34 + (ty<<2));
      float2 w23 = *(const float2*)(Ws + (size_t)k*34 + (ty<<2) + 2);
      acc0.x = fmaf(a.x, w01.x, acc0.x); acc0.y = fmaf(a.x, w01.y, acc0.y);
      acc0.z = fmaf(a.x, w23.x, acc0.z); acc0.w = fmaf(a.x, w23.y, acc0.w);
      acc1.x = fmaf(a.y, w01.x, acc1.x); acc1.y = fmaf(a.y, w01.y, acc1.y);
      acc1.z = fmaf(a.y, w23.x, acc1.z); acc1.w = fmaf(a.y, w23.y, acc1.w);
      acc2.x = fmaf(a.z, w01.x, acc2.x); acc2.y = fmaf(a.z, w01.y, acc2.y);
      acc2.z = fmaf(a.z, w23.x, acc2.z); acc2.w = fmaf(a.z, w23.y, acc2.w);
      acc3.x = fmaf(a.w, w01.x, acc3.x); acc3.y = fmaf(a.w, w01.y, acc3.y);
      acc3.z = fmaf(a.w, w23.x, acc3.z); acc3.w = fmaf(a.w, w23.y, acc3.w);
    }
    int j0 = (cc << 5) + (ty << 2);
    float4 b4 = make_float4(0,0,0,0);
    if (bias) b4 = *(const float4*)(bias + j0);
    float4 r[4] = {acc0, acc1, acc2, acc3};
    #pragma unroll
    for (int i = 0; i < 4; ++i){
      int n = nb + (tx<<2) + i;
      if (n < N){
        float4 o;
        o.x = r[i].x + b4.x; o.y = r[i].y + b4.y; o.z = r[i].z + b4.z; o.w = r[i].w + b4.w;
        if (act){
          o.x = fmaxf(o.x, 0.f); o.y = fmaxf(o.y, 0.f);
          o.z = fmaxf(o.z, 0.f); o.w = fmaxf(o.w, 0.f);
        }
        *(float4*)(out + (size_t)n*JC + j0) = o;
      }
    }
  }
}

// ---------------- LSTM weight prepack: fragment-linear bf16, SINGLE plane ----------------
// Wp index = ((kt*12 + rt)*64 + l)*8 + i
__global__ __launch_bounds__(256) void k_packW1(const float* __restrict__ Wih, const float* __restrict__ Whh,
                                                u16* __restrict__ Wp){
  int idx = blockIdx.x*256 + threadIdx.x;
  if (idx >= 10*12*64*8) return;
  int i  = idx & 7;
  int l  = (idx>>3) & 63;
  int rt = (idx>>9) % 12;
  int kt = (idx>>9) / 12;
  int r  = rt*32 + (l & 31);
  int j  = r >> 2, g = r & 3;
  int row = g*96 + j;
  int k  = kt*16 + ((l>>5)<<3) + i;
  float v = (k < 64) ? Wih[row*64 + k] : Whh[row*96 + (k-64)];
  Wp[idx] = f2bf(v);
}

__global__ __launch_bounds__(128) void k_packB(const float* __restrict__ bih, const float* __restrict__ bhh,
                                               float4* __restrict__ Bp){
  int j = blockIdx.x*128 + threadIdx.x;
  if (j >= 96) return;
  Bp[j] = make_float4(bih[j]+bhh[j], bih[96+j]+bhh[96+j],
                      bih[192+j]+bhh[192+j], bih[288+j]+bhh[288+j]);
}

// ---------------- MFMA LSTM v5b: 256 thr / 4 waves / 32 nodes / single-buffered A ----------------
__device__ __forceinline__ void ldx_regs(const float* __restrict__ seq, int blk, int N, int tid,
                                         float (&v)[8]){
  int node = tid >> 3;         // 0..31
  int kc = tid & 7;
  int n = blk*32 + node;
  if (n < N){
    const float4* s4 = (const float4*)(seq + (size_t)n*64 + kc*8);
    float4 a = s4[0], b = s4[1];
    v[0]=a.x; v[1]=a.y; v[2]=a.z; v[3]=a.w; v[4]=b.x; v[5]=b.y; v[6]=b.z; v[7]=b.w;
  } else {
    #pragma unroll
    for (int i=0;i<8;++i) v[i]=0.f;
  }
}

__device__ __forceinline__ void cvt8p(const float (&v)[8], u32 (&hw)[4], u32 (&lw)[4]){
  #pragma unroll
  for (int i=0;i<4;++i){
    u16 h0=f2bf(v[2*i]),   h1=f2bf(v[2*i+1]);
    u16 l0=f2bf(v[2*i]-bf2f(h0)), l1=f2bf(v[2*i+1]-bf2f(h1));
    hw[i]= (u32)h0 | ((u32)h1<<16);
    lw[i]= (u32)l0 | ((u32)l1<<16);
  }
}

__device__ __forceinline__ void stage_from_regs(const float (&v)[8], u16* __restrict__ XH,
                                                u16* __restrict__ XL, int tid){
  int node = tid >> 3;
  int kc = tid & 7;            // kc = kt*2 + hi
  u32 hw[4], lw[4];
  cvt8p(v, hw, lw);
  int kt = kc >> 1, hi = kc & 1;
  int sl = (((hi<<5) | node) ^ (kc & 7));
  int addr = (kt<<9) + (sl<<3);
  *(uint4*)(XH + addr) = make_uint4(hw[0],hw[1],hw[2],hw[3]);
  *(uint4*)(XL + addr) = make_uint4(lw[0],lw[1],lw[2],lw[3]);
}

__device__ __forceinline__ void restage_h(const float (*hF)[32], u16* __restrict__ XH,
                                          u16* __restrict__ XL, int tid){
  int node = tid & 31;
  #pragma unroll
  for (int q = 0; q < 2; ++q){
    int cc = (tid >> 5) + q*8;
    if (cc < 12){
      int kth = cc >> 1, hi = cc & 1;
      int ktG = kth + 4;
      float v[8];
      #pragma unroll
      for (int i=0;i<8;++i) v[i] = hF[cc*8 + i][node];
      u32 hw[4], lw[4];
      cvt8p(v, hw, lw);
      int sl = (((hi<<5) | node) ^ ((2*ktG + hi) & 7));
      int addr = (ktG<<9) + (sl<<3);
      *(uint4*)(XH + addr) = make_uint4(hw[0],hw[1],hw[2],hw[3]);
      *(uint4*)(XL + addr) = make_uint4(lw[0],lw[1],lw[2],lw[3]);
    }
  }
}

template<int FIRST, int WRITEH>
__device__ __forceinline__ float lstm_step5(const u16* __restrict__ Wp,
    const float4* __restrict__ Bp, const float* __restrict__ WattW,
    const u16* __restrict__ XH, const u16* __restrict__ XL, float (*hF)[32],
    float (&c)[12], int rtg, int l)
{
  constexpr int NKT = FIRST ? 4 : 10;
  const int hi = l >> 5;
  const int col = l & 31;
  f32x16 acc[3];
  #pragma unroll
  for (int t=0;t<3;++t)
    #pragma unroll
    for (int r=0;r<16;++r) acc[t][r] = 0.f;

  const u16* wbase = Wp + (size_t)(rtg*3)*512 + ((size_t)l<<3);
  #pragma unroll
  for (int kt = 0; kt < NKT; ++kt){
    const u16* wk = wbase + (size_t)kt*6144;
    short8 A0 = *(const short8*)(wk);
    short8 A1 = *(const short8*)(wk + 512);
    short8 A2 = *(const short8*)(wk + 1024);
    int sl = l ^ (((kt<<1) + hi) & 7);
    int baddr = (kt<<9) + (sl<<3);
    short8 Bh = *(const short8*)(XH + baddr);
    short8 Bl = *(const short8*)(XL + baddr);
    __builtin_amdgcn_s_setprio(1);
    acc[0] = __builtin_amdgcn_mfma_f32_32x32x16_bf16(A0, Bh, acc[0], 0,0,0);
    acc[1] = __builtin_amdgcn_mfma_f32_32x32x16_bf16(A1, Bh, acc[1], 0,0,0);
    acc[2] = __builtin_amdgcn_mfma_f32_32x32x16_bf16(A2, Bh, acc[2], 0,0,0);
    acc[0] = __builtin_amdgcn_mfma_f32_32x32x16_bf16(A0, Bl, acc[0], 0,0,0);
    acc[1] = __builtin_amdgcn_mfma_f32_32x32x16_bf16(A1, Bl, acc[1], 0,0,0);
    acc[2] = __builtin_amdgcn_mfma_f32_32x32x16_bf16(A2, Bl, acc[2], 0,0,0);
    __builtin_amdgcn_s_setprio(0);
  }

  float aP = 0.f;
  #pragma unroll
  for (int ti=0;ti<3;++ti){
    #pragma unroll
    for (int rg=0; rg<4; ++rg){
      const int j = (rtg*3+ti)*8 + 2*rg + hi;
      float4 bv = Bp[j];
      float gi = acc[ti][rg*4+0] + bv.x;
      float gf = acc[ti][rg*4+1] + bv.y;
      float gg = acc[ti][rg*4+2] + bv.z;
      float go = acc[ti][rg*4+3] + bv.w;
      const int ci = ti*4 + rg;
      float cp = FIRST ? 0.f : c[ci];
      float cn = sigf(gf)*cp + sigf(gi)*tanh_f(gg);
      float hh = sigf(go)*tanh_f(cn);
      c[ci] = cn;
      aP = fmaf(hh, WattW[j], aP);
      if (WRITEH) hF[j][col] = hh;
    }
  }
  return aP;
}

__global__ __launch_bounds__(256,2) void k_lstm5(
    const float* __restrict__ h1, const float* __restrict__ h2, const float* __restrict__ h3,
    const u16* __restrict__ Wpf, const u16* __restrict__ Wpb,
    const float4* __restrict__ Bpf, const float4* __restrict__ Bpb,
    const float* __restrict__ Watt, const float* __restrict__ batt,
    float* __restrict__ aF, float* __restrict__ aB, int gL, int N)
{
  __shared__ u16 XH[5120];
  __shared__ u16 XL[5120];
  __shared__ float hF[96][32];
  __shared__ float sAl[4][3][32];
  const int tid = threadIdx.x;
  const int l = tid & 63;
  const int rtg = __builtin_amdgcn_readfirstlane(tid >> 6);
  const int dir = (blockIdx.x >= gL) ? 1 : 0;
  const int blk = blockIdx.x - dir*gL;
  const float* sA = dir ? h3 : h1;
  const float* sC = dir ? h1 : h3;
  const u16* Wp = dir ? Wpb : Wpf;
  const float4* Bp = dir ? Bpb : Bpf;
  const float* WattW = Watt + dir*96;
  float* aD = dir ? aB : aF;
  float c[12];
  float a0, a1, a2;
  float xv[8];

  // prologue: stage x0; pre-issue x1 loads
  ldx_regs(sA, blk, N, tid, xv);
  stage_from_regs(xv, XH, XL, tid);
  ldx_regs(h2, blk, N, tid, xv);
  __syncthreads();

  a0 = lstm_step5<1,1>(Wp, Bp, WattW, XH, XL, hF, c, rtg, l);
  __syncthreads();
  stage_from_regs(xv, XH, XL, tid);
  restage_h(hF, XH, XL, tid);
  ldx_regs(sC, blk, N, tid, xv);
  __syncthreads();

  a1 = lstm_step5<0,1>(Wp, Bp, WattW, XH, XL, hF, c, rtg, l);
  __syncthreads();
  stage_from_regs(xv, XH, XL, tid);
  restage_h(hF, XH, XL, tid);
  __syncthreads();

  a2 = lstm_step5<0,0>(Wp, Bp, WattW, XH, XL, hF, c, rtg, l);

  // alpha reduce: lanes l and l^32 hold complementary gate halves of same node
  a0 += __shfl_xor(a0, 32);
  a1 += __shfl_xor(a1, 32);
  a2 += __shfl_xor(a2, 32);
  if (l < 32){
    sAl[rtg][0][l] = a0;
    sAl[rtg][1][l] = a1;
    sAl[rtg][2][l] = a2;
  }
  __syncthreads();
  if (tid < 96){
    int s = tid >> 5;
    int node = tid & 31;
    int n = blk*32 + node;
    if (n < N){
      float sum = sAl[0][s][node] + sAl[1][s][node]
                + sAl[2][s][node] + sAl[3][s][node];
      int slice = dir ? (2 - s) : s;
      float v = dir ? sum : (batt[0] + sum);
      aD[(size_t)slice*N + n] = v;
    }
  }
}

// ---------------- JK softmax + xjk + Wlin + Wfc1 + leaky (64 nodes/block) ----------------
__global__ __launch_bounds__(256) void k_jk(const float* __restrict__ aF, const float* __restrict__ aB,
                                            const float* __restrict__ h1, const float* __restrict__ h2,
                                            const float* __restrict__ h3,
                                            const float* __restrict__ Wlin, const float* __restrict__ blin,
                                            const float* __restrict__ Wfc1, const float* __restrict__ bfc1,
                                            float* __restrict__ vout, int N){
  __shared__ float sWl[64*65];
  __shared__ float sX[4][64];
  int tid = threadIdx.x;
  for (int idx = tid; idx < 1024; idx += 256){
    int j = idx >> 4;
    int c4 = (idx & 15) << 2;
    float4 v = *(const float4*)(Wlin + (size_t)j*64 + c4);
    sWl[j*65 + c4+0] = v.x; sWl[j*65 + c4+1] = v.y;
    sWl[j*65 + c4+2] = v.z; sWl[j*65 + c4+3] = v.w;
  }
  __syncthreads();
  int ln = tid >> 6, j = tid & 63;
  float wf1 = Wfc1[j];
  float bl = blin[j];
  for (int ib = 0; ib < 16; ++ib){
    int n = blockIdx.x*64 + ib*4 + ln;
    bool ok = n < N;
    float xj = 0.f;
    if (ok){
      float a0 = aF[n] + aB[n];
      float a1 = aF[(size_t)N + n] + aB[(size_t)N + n];
      float a2 = aF[(size_t)2*N + n] + aB[(size_t)2*N + n];
      float m = fmaxf(a0, fmaxf(a1, a2));
      float e0 = __expf(a0-m), e1 = __expf(a1-m), e2 = __expf(a2-m);
      float inv = __builtin_amdgcn_rcpf(e0+e1+e2);
      float w0 = e0*inv, w1 = e1*inv, w2 = e2*inv;
      xj = w0*h1[(size_t)n*64 + j] + w1*h2[(size_t)n*64 + j] + w2*h3[(size_t)n*64 + j];
    }
    sX[ln][j] = xj;
    __syncthreads();
    float acc = bl;
    #pragma unroll 8
    for (int cc = 0; cc < 64; ++cc) acc = fmaf(sX[ln][cc], sWl[j*65 + cc], acc);
    float r = acc * wf1;
    #pragma unroll
    for (int off = 32; off > 0; off >>= 1) r += __shfl_down(r, off);
    if (j == 0 && ok){
      float vv = r + bfc1[0];
      vout[n] = vv >= 0.f ? vv : 0.01f*vv;
    }
    __syncthreads();
  }
}

// ---------------- final dot (deterministic two-stage, f64 accum) ----------------
__global__ __launch_bounds__(256) void k_final1(const float* __restrict__ w, const float* __restrict__ v,
                                                double* __restrict__ part, int N){
  __shared__ double sd[256];
  int tid = threadIdx.x;
  double a = 0.0;
  for (int i = blockIdx.x*256 + tid; i < N; i += 256*256)
    a += (double)(w[i] * v[i]);
  sd[tid] = a; __syncthreads();
  for (int off = 128; off > 0; off >>= 1){
    if (tid < off) sd[tid] += sd[tid + off];
    __syncthreads();
  }
  if (tid == 0) part[blockIdx.x] = sd[0];
}

__global__ __launch_bounds__(256) void k_final2(const double* __restrict__ part, const float* __restrict__ bfc2,
                                                float* __restrict__ out){
  __shared__ double sd[256];
  int tid = threadIdx.x;
  sd[tid] = part[tid]; __syncthreads();
  for (int off = 128; off > 0; off >>= 1){
    if (tid < off) sd[tid] += sd[tid + off];
    __syncthreads();
  }
  if (tid == 0) out[0] = (float)(sd[0] + (double)bfc2[0]);
}

// ---------------- host ----------------
extern "C" void kernel_launch(void* const* d_in, const int* in_sizes, int n_in,
                              void* d_out, int out_size, void* d_ws, size_t ws_size,
                              hipStream_t stream){
  const float* x    = (const float*)d_in[0];
  const int*   ei   = (const int*)d_in[1];
  const float* W0a  = (const float*)d_in[2];
  const float* b0a  = (const float*)d_in[3];
  const float* W0b  = (const float*)d_in[4];
  const float* b0b  = (const float*)d_in[5];
  const float* W1a  = (const float*)d_in[6];
  const float* b1a  = (const float*)d_in[7];
  const float* W1b  = (const float*)d_in[8];
  const float* b1b  = (const float*)d_in[9];
  const float* W2a  = (const float*)d_in[10];
  const float* b2a  = (const float*)d_in[11];
  const float* W2b  = (const float*)d_in[12];
  const float* b2b  = (const float*)d_in[13];
  const float* Wih_f = (const float*)d_in[14];
  const float* Whh_f = (const float*)d_in[15];
  const float* bih_f = (const float*)d_in[16];
  const float* bhh_f = (const float*)d_in[17];
  const float* Wih_b = (const float*)d_in[18];
  const float* Whh_b = (const float*)d_in[19];
  const float* bih_b = (const float*)d_in[20];
  const float* bhh_b = (const float*)d_in[21];
  const float* Watt = (const float*)d_in[22];
  const float* batt = (const float*)d_in[23];
  const float* Wlin = (const float*)d_in[24];
  const float* blin = (const float*)d_in[25];
  const float* Wfc1 = (const float*)d_in[26];
  const float* bfc1 = (const float*)d_in[27];
  const float* Wfc2 = (const float*)d_in[28];
  const float* bfc2 = (const float*)d_in[29];
  float* out = (float*)d_out;

  const int N = in_sizes[0] / 128;
  const int E = in_sizes[1] / 2;
  const int* src = ei;
  const int* dst = ei + E;

  uint8_t* w8 = (uint8_t*)d_ws;
  size_t off = 0;
  auto alloc = [&](size_t bytes) -> void* {
    void* p = w8 + off;
    off = (off + bytes + 255) & ~(size_t)255;
    return p;
  };
  int*    deg    = (int*)   alloc((size_t)N*4);
  int*    fill   = (int*)   alloc((size_t)N*4);
  int*    indptr = (int*)   alloc(((size_t)N+1)*4);
  int*    col    = (int*)   alloc((size_t)E*4);
  int*    bsum   = (int*)   alloc(2048);
  int*    boffs  = (int*)   alloc(2048);
  float*  h1     = (float*) alloc((size_t)N*64*4);
  float*  h2     = (float*) alloc((size_t)N*64*4);
  float*  h3     = (float*) alloc((size_t)N*64*4);
  float*  aF     = (float*) alloc((size_t)3*N*4);
  float*  aB     = (float*) alloc((size_t)3*N*4);
  float*  vbuf   = (float*) alloc((size_t)N*4);
  double* part   = (double*)alloc(256*8);
  u16*    Wpf    = (u16*)   alloc((size_t)10*12*64*8*2);
  u16*    Wpb    = (u16*)   alloc((size_t)10*12*64*8*2);
  float4* Bpf    = (float4*)alloc((size_t)96*16);
  float4* Bpb    = (float4*)alloc((size_t)96*16);
  float*  P      = (float*) alloc((size_t)N*192*4);
  if (off > ws_size) return;
  float* ybuf = P;
  float* zbuf = P + (size_t)N*64;

  const size_t lds64  = 64  * 102 * 4;
  const size_t lds128 = 128 * 102 * 4;

  hipMemsetAsync(deg,  0, (size_t)N*4, stream);
  hipMemsetAsync(fill, 0, (size_t)N*4, stream);

  int gE = (E + 255) / 256;
  int nb1 = (N + 255) / 256;
  int gG = (N + 63) / 64;
  int gAg = (N + 31) / 32;
  int gL = (N + 31) / 32;

  // weight prepack (independent of CSR)
  k_packW1<<<240, 256, 0, stream>>>(Wih_f, Whh_f, Wpf);
  k_packW1<<<240, 256, 0, stream>>>(Wih_b, Whh_b, Wpb);
  k_packB<<<1, 128, 0, stream>>>(bih_f, bhh_f, Bpf);
  k_packB<<<1, 128, 0, stream>>>(bih_b, bhh_b, Bpb);

  k_deg  <<<gE, 256, 0, stream>>>(dst, deg, E);
  k_scan1<<<nb1, 256, 0, stream>>>(deg, indptr, bsum, N);
  k_scan2<<<1, 512, 0, stream>>>(bsum, boffs, indptr, nb1, N);
  k_scan3<<<nb1, 256, 0, stream>>>(indptr, boffs, N);
  k_fill <<<gE, 256, 0, stream>>>(src, dst, indptr, fill, col, E);

  // ---- GIN layer 0 (transform-first: (x+aggX)@W = y+aggY) ----
  k_gemm<<<gG, TPB, lds128, stream>>>(x, W0a, nullptr, ybuf, 128, 64, 0, N);
  k_agg2<<<gAg, 256, 0, stream>>>(ybuf, indptr, col, b0a, zbuf, N);
  k_gemm<<<gG, TPB, lds64, stream>>>(zbuf, W0b, b0b, h1, 64, 64, 1, N);
  // ---- GIN layer 1 ----
  k_gemm<<<gG, TPB, lds64, stream>>>(h1, W1a, nullptr, ybuf, 64, 64, 0, N);
  k_agg2<<<gAg, 256, 0, stream>>>(ybuf, indptr, col, b1a, zbuf, N);
  k_gemm<<<gG, TPB, lds64, stream>>>(zbuf, W1b, b1b, h2, 64, 64, 1, N);
  // ---- GIN layer 2 ----
  k_gemm<<<gG, TPB, lds64, stream>>>(h2, W2a, nullptr, ybuf, 64, 64, 0, N);
  k_agg2<<<gAg, 256, 0, stream>>>(ybuf, indptr, col, b2a, zbuf, N);
  k_gemm<<<gG, TPB, lds64, stream>>>(zbuf, W2b, b2b, h3, 64, 64, 1, N);

  // ---- LSTM: both directions in one dispatch ----
  k_lstm5<<<2*gL, 256, 0, stream>>>(h1, h2, h3, Wpf, Wpb, Bpf, Bpb, Watt, batt,
                                    aF, aB, gL, N);

  // ---- JK attention + linear + fc1 + leaky ----
  k_jk<<<(N+63)/64, 256, 0, stream>>>(aF, aB, h1, h2, h3, Wlin, blin, Wfc1, bfc1, vbuf, N);

  // ---- final dot ----
  k_final1<<<256, 256, 0, stream>>>(Wfc2, vbuf, part, N);
  k_final2<<<1, 256, 0, stream>>>(part, bfc2, out);
}

// Round 13
// 696.491 us; speedup vs baseline: 1.2112x; 1.2112x over previous
//
#include <hip/hip_runtime.h>
#include <stdint.h>

typedef unsigned short u16;
typedef unsigned int u32;
using short8 = __attribute__((ext_vector_type(8))) short;
using f32x16 = __attribute__((ext_vector_type(16))) float;

__device__ __forceinline__ float sigf(float x){
  return __builtin_amdgcn_rcpf(1.0f + __expf(-x));
}
__device__ __forceinline__ float tanh_f(float x){
  return 1.0f - 2.0f*__builtin_amdgcn_rcpf(1.0f + __expf(2.0f*x));
}
__device__ __forceinline__ u16 f2bf(float f){
  u32 u = __float_as_uint(f);
  u += 0x7FFFu + ((u>>16)&1u);
  return (u16)(u>>16);
}
__device__ __forceinline__ float bf2f(u16 h){ return __uint_as_float(((u32)h)<<16); }

// ---------------- CSR build ----------------
__global__ void k_deg(const int* __restrict__ dst, int* __restrict__ deg, int E){
  int i = blockIdx.x*256 + threadIdx.x;
  if (i < E) atomicAdd(&deg[dst[i]], 1);
}

__global__ __launch_bounds__(256) void k_scan1(const int* __restrict__ deg, int* __restrict__ indptr,
                                               int* __restrict__ bsum, int N){
  __shared__ int s[256];
  int tid = threadIdx.x;
  int i = blockIdx.x*256 + tid;
  int v = (i < N) ? deg[i] : 0;
  s[tid] = v; __syncthreads();
  for (int off=1; off<256; off<<=1){
    int t = (tid>=off) ? s[tid-off] : 0;
    __syncthreads();
    s[tid] += t;
    __syncthreads();
  }
  if (i < N) indptr[i] = s[tid] - v;
  if (tid == 255) bsum[blockIdx.x] = s[255];
}

__global__ __launch_bounds__(512) void k_scan2(const int* __restrict__ bsum, int* __restrict__ boffs,
                                               int* __restrict__ indptr, int nb, int N){
  __shared__ int s[512];
  int tid = threadIdx.x;
  int v = (tid < nb) ? bsum[tid] : 0;
  s[tid] = v; __syncthreads();
  for (int off=1; off<512; off<<=1){
    int t = (tid>=off) ? s[tid-off] : 0;
    __syncthreads();
    s[tid] += t;
    __syncthreads();
  }
  boffs[tid] = s[tid] - v;
  if (tid == nb-1) indptr[N] = s[tid];
}

__global__ __launch_bounds__(256) void k_scan3(int* __restrict__ indptr, const int* __restrict__ boffs, int N){
  int i = blockIdx.x*256 + threadIdx.x;
  if (i < N) indptr[i] += boffs[blockIdx.x];
}

__global__ void k_fill(const int* __restrict__ src, const int* __restrict__ dst,
                       const int* __restrict__ indptr, int* __restrict__ fill,
                       int* __restrict__ col, int E){
  int i = blockIdx.x*256 + threadIdx.x;
  if (i < E){
    int d = dst[i];
    int r = atomicAdd(&fill[d], 1);
    col[indptr[d] + r] = src[i];
  }
}

// ---------------- aggregation (round-10 proven): z[n] = relu( y[n] + sum y[src] + b ) ----------------
template<int F>
__global__ __launch_bounds__(256) void k_agg(const float* __restrict__ y, const int* __restrict__ indptr,
                                             const int* __restrict__ col, const float* __restrict__ bias,
                                             float* __restrict__ z, int N){
  constexpr int TPN = F/4;
  constexpr int NPB = 256/TPN;
  int n = blockIdx.x*NPB + threadIdx.x/TPN;
  int lane = threadIdx.x % TPN;
  if (n >= N) return;
  const float4* hv = (const float4*)y;
  float4 acc = hv[(size_t)n*TPN + lane];
  int s = indptr[n], e = indptr[n+1];
  int p = s;
  for (; p + 8 <= e; p += 8){
    int c8[8];
    #pragma unroll
    for (int i=0;i<8;++i) c8[i] = col[p+i];
    #pragma unroll
    for (int i=0;i<8;++i){
      float4 x = hv[(size_t)c8[i]*TPN + lane];
      acc.x += x.x; acc.y += x.y; acc.z += x.z; acc.w += x.w;
    }
  }
  for (; p < e; ++p){
    float4 x = hv[(size_t)col[p]*TPN + lane];
    acc.x += x.x; acc.y += x.y; acc.z += x.z; acc.w += x.w;
  }
  float4 b4 = ((const float4*)bias)[lane];
  acc.x = fmaxf(acc.x + b4.x, 0.f);
  acc.y = fmaxf(acc.y + b4.y, 0.f);
  acc.z = fmaxf(acc.z + b4.z, 0.f);
  acc.w = fmaxf(acc.w + b4.w, 0.f);
  ((float4*)z)[(size_t)n*TPN + lane] = acc;
}

// ---------------- GIN GEMM weight prepack: frag-linear bf16 hi/lo ----------------
// Wg index = ((kt*2 + rt)*2 + p)*512 + l*8 + i ; j = rt*32+(l&31), k = kt*16+(l>>5)*8+i
__global__ __launch_bounds__(256) void k_packG(const float* __restrict__ W, u16* __restrict__ Wg, int K){
  int idx = blockIdx.x*256 + threadIdx.x;
  if (idx >= K*128) return;
  int i  = idx & 7;
  int l  = (idx>>3) & 63;
  int p  = (idx>>9) & 1;
  int rt = (idx>>10) & 1;
  int kt = idx >> 11;
  int j  = rt*32 + (l & 31);
  int k  = kt*16 + ((l>>5)<<3) + i;
  float v = W[(size_t)j*K + k];
  u16 h = f2bf(v);
  Wg[idx] = p ? f2bf(v - bf2f(h)) : h;
}

__device__ __forceinline__ void cvt8p(const float (&v)[8], u32 (&hw)[4], u32 (&lw)[4]){
  #pragma unroll
  for (int i=0;i<4;++i){
    u16 h0=f2bf(v[2*i]),   h1=f2bf(v[2*i+1]);
    u16 l0=f2bf(v[2*i]-bf2f(h0)), l1=f2bf(v[2*i+1]-bf2f(h1));
    hw[i]= (u32)h0 | ((u32)h1<<16);
    lw[i]= (u32)l0 | ((u32)l1<<16);
  }
}

// ---------------- MFMA GEMM: out[n][j] = act( sum_k A[n][k] W[j][k] + b[j] ), JC=64 ----------------
// 64 nodes/block, 4 waves = (rt = w>>1, nt = w&1) quadrants. A staged bf16 hi/lo frag-linear in LDS
// (swizzle (kt*2+hi)&7, 2-way max = free); W frags streamed from L2; 3 MFMA/kt (hi/lo split).
template<int K, int ACT>
__global__ __launch_bounds__(256,2) void k_mfgemm(const float* __restrict__ A, const u16* __restrict__ Wg,
                                                  const float* __restrict__ bias, float* __restrict__ out,
                                                  int N){
  constexpr int NKT = K/16;
  __shared__ u16 BH[2*NKT*512];
  __shared__ u16 BL[2*NKT*512];
  const int tid = threadIdx.x;
  const int l = tid & 63;
  const int w = __builtin_amdgcn_readfirstlane(tid >> 6);
  const int rt = w >> 1, nt = w & 1;
  const int nb = blockIdx.x * 64;
  const int hi = l >> 5;

  // stage A -> bf16 hi/lo fragment planes
  for (int u = tid; u < 64*(K/8); u += 256){
    int node = u / (K/8);
    int kc = u % (K/8);
    int n = nb + node;
    float v[8];
    if (n < N){
      const float4* s4 = (const float4*)(A + (size_t)n*K + kc*8);
      float4 a = s4[0], b = s4[1];
      v[0]=a.x; v[1]=a.y; v[2]=a.z; v[3]=a.w; v[4]=b.x; v[5]=b.y; v[6]=b.z; v[7]=b.w;
    } else {
      #pragma unroll
      for (int i=0;i<8;++i) v[i]=0.f;
    }
    u32 hw[4], lw[4];
    cvt8p(v, hw, lw);
    int kt = kc >> 1, h2 = kc & 1;
    int sl = (((h2<<5) | (node&31)) ^ (kc & 7));
    int addr = (((node>>5)*NKT + kt)<<9) + (sl<<3);
    *(uint4*)(BH + addr) = make_uint4(hw[0],hw[1],hw[2],hw[3]);
    *(uint4*)(BL + addr) = make_uint4(lw[0],lw[1],lw[2],lw[3]);
  }
  __syncthreads();

  f32x16 acc;
  #pragma unroll
  for (int r=0;r<16;++r) acc[r] = 0.f;
  const u16* wbase = Wg + ((size_t)rt<<10) + ((size_t)l<<3);
  #pragma unroll
  for (int kt = 0; kt < NKT; ++kt){
    const u16* wk = wbase + (size_t)kt*2048;
    short8 Ah = *(const short8*)(wk);
    short8 Al = *(const short8*)(wk + 512);
    int sl = l ^ (((kt<<1) + hi) & 7);
    int baddr = ((nt*NKT + kt)<<9) + (sl<<3);
    short8 Bh = *(const short8*)(BH + baddr);
    short8 Bl = *(const short8*)(BL + baddr);
    acc = __builtin_amdgcn_mfma_f32_32x32x16_bf16(Ah, Bh, acc, 0,0,0);
    acc = __builtin_amdgcn_mfma_f32_32x32x16_bf16(Ah, Bl, acc, 0,0,0);
    acc = __builtin_amdgcn_mfma_f32_32x32x16_bf16(Al, Bh, acc, 0,0,0);
  }

  const int col = l & 31;
  const int n = nb + nt*32 + col;
  if (n < N){
    #pragma unroll
    for (int g = 0; g < 4; ++g){
      const int j0 = rt*32 + 8*g + 4*hi;
      float4 b4 = bias ? *(const float4*)(bias + j0) : make_float4(0.f,0.f,0.f,0.f);
      float4 o;
      o.x = acc[4*g+0] + b4.x;
      o.y = acc[4*g+1] + b4.y;
      o.z = acc[4*g+2] + b4.z;
      o.w = acc[4*g+3] + b4.w;
      if (ACT){
        o.x = fmaxf(o.x, 0.f); o.y = fmaxf(o.y, 0.f);
        o.z = fmaxf(o.z, 0.f); o.w = fmaxf(o.w, 0.f);
      }
      *(float4*)(out + (size_t)n*64 + j0) = o;
    }
  }
}

// ---------------- LSTM weight prepack: fragment-linear bf16, SINGLE plane ----------------
__global__ __launch_bounds__(256) void k_packW1(const float* __restrict__ Wih, const float* __restrict__ Whh,
                                                u16* __restrict__ Wp){
  int idx = blockIdx.x*256 + threadIdx.x;
  if (idx >= 10*12*64*8) return;
  int i  = idx & 7;
  int l  = (idx>>3) & 63;
  int rt = (idx>>9) % 12;
  int kt = (idx>>9) / 12;
  int r  = rt*32 + (l & 31);
  int j  = r >> 2, g = r & 3;
  int row = g*96 + j;
  int k  = kt*16 + ((l>>5)<<3) + i;
  float v = (k < 64) ? Wih[row*64 + k] : Whh[row*96 + (k-64)];
  Wp[idx] = f2bf(v);
}

__global__ __launch_bounds__(128) void k_packB(const float* __restrict__ bih, const float* __restrict__ bhh,
                                               float4* __restrict__ Bp){
  int j = blockIdx.x*128 + threadIdx.x;
  if (j >= 96) return;
  Bp[j] = make_float4(bih[j]+bhh[j], bih[96+j]+bhh[96+j],
                      bih[192+j]+bhh[192+j], bih[288+j]+bhh[288+j]);
}

// ---------------- MFMA LSTM v5b (proven 216 us) ----------------
__device__ __forceinline__ void ldx_regs(const float* __restrict__ seq, int blk, int N, int tid,
                                         float (&v)[8]){
  int node = tid >> 3;
  int kc = tid & 7;
  int n = blk*32 + node;
  if (n < N){
    const float4* s4 = (const float4*)(seq + (size_t)n*64 + kc*8);
    float4 a = s4[0], b = s4[1];
    v[0]=a.x; v[1]=a.y; v[2]=a.z; v[3]=a.w; v[4]=b.x; v[5]=b.y; v[6]=b.z; v[7]=b.w;
  } else {
    #pragma unroll
    for (int i=0;i<8;++i) v[i]=0.f;
  }
}

__device__ __forceinline__ void stage_from_regs(const float (&v)[8], u16* __restrict__ XH,
                                                u16* __restrict__ XL, int tid){
  int node = tid >> 3;
  int kc = tid & 7;
  u32 hw[4], lw[4];
  cvt8p(v, hw, lw);
  int kt = kc >> 1, hi = kc & 1;
  int sl = (((hi<<5) | node) ^ (kc & 7));
  int addr = (kt<<9) + (sl<<3);
  *(uint4*)(XH + addr) = make_uint4(hw[0],hw[1],hw[2],hw[3]);
  *(uint4*)(XL + addr) = make_uint4(lw[0],lw[1],lw[2],lw[3]);
}

__device__ __forceinline__ void restage_h(const float (*hF)[32], u16* __restrict__ XH,
                                          u16* __restrict__ XL, int tid){
  int node = tid & 31;
  #pragma unroll
  for (int q = 0; q < 2; ++q){
    int cc = (tid >> 5) + q*8;
    if (cc < 12){
      int kth = cc >> 1, hi = cc & 1;
      int ktG = kth + 4;
      float v[8];
      #pragma unroll
      for (int i=0;i<8;++i) v[i] = hF[cc*8 + i][node];
      u32 hw[4], lw[4];
      cvt8p(v, hw, lw);
      int sl = (((hi<<5) | node) ^ ((2*ktG + hi) & 7));
      int addr = (ktG<<9) + (sl<<3);
      *(uint4*)(XH + addr) = make_uint4(hw[0],hw[1],hw[2],hw[3]);
      *(uint4*)(XL + addr) = make_uint4(lw[0],lw[1],lw[2],lw[3]);
    }
  }
}

template<int FIRST, int WRITEH>
__device__ __forceinline__ float lstm_step5(const u16* __restrict__ Wp,
    const float4* __restrict__ Bp, const float* __restrict__ WattW,
    const u16* __restrict__ XH, const u16* __restrict__ XL, float (*hF)[32],
    float (&c)[12], int rtg, int l)
{
  constexpr int NKT = FIRST ? 4 : 10;
  const int hi = l >> 5;
  const int col = l & 31;
  f32x16 acc[3];
  #pragma unroll
  for (int t=0;t<3;++t)
    #pragma unroll
    for (int r=0;r<16;++r) acc[t][r] = 0.f;

  const u16* wbase = Wp + (size_t)(rtg*3)*512 + ((size_t)l<<3);
  #pragma unroll
  for (int kt = 0; kt < NKT; ++kt){
    const u16* wk = wbase + (size_t)kt*6144;
    short8 A0 = *(const short8*)(wk);
    short8 A1 = *(const short8*)(wk + 512);
    short8 A2 = *(const short8*)(wk + 1024);
    int sl = l ^ (((kt<<1) + hi) & 7);
    int baddr = (kt<<9) + (sl<<3);
    short8 Bh = *(const short8*)(XH + baddr);
    short8 Bl = *(const short8*)(XL + baddr);
    __builtin_amdgcn_s_setprio(1);
    acc[0] = __builtin_amdgcn_mfma_f32_32x32x16_bf16(A0, Bh, acc[0], 0,0,0);
    acc[1] = __builtin_amdgcn_mfma_f32_32x32x16_bf16(A1, Bh, acc[1], 0,0,0);
    acc[2] = __builtin_amdgcn_mfma_f32_32x32x16_bf16(A2, Bh, acc[2], 0,0,0);
    acc[0] = __builtin_amdgcn_mfma_f32_32x32x16_bf16(A0, Bl, acc[0], 0,0,0);
    acc[1] = __builtin_amdgcn_mfma_f32_32x32x16_bf16(A1, Bl, acc[1], 0,0,0);
    acc[2] = __builtin_amdgcn_mfma_f32_32x32x16_bf16(A2, Bl, acc[2], 0,0,0);
    __builtin_amdgcn_s_setprio(0);
  }

  float aP = 0.f;
  #pragma unroll
  for (int ti=0;ti<3;++ti){
    #pragma unroll
    for (int rg=0; rg<4; ++rg){
      const int j = (rtg*3+ti)*8 + 2*rg + hi;
      float4 bv = Bp[j];
      float gi = acc[ti][rg*4+0] + bv.x;
      float gf = acc[ti][rg*4+1] + bv.y;
      float gg = acc[ti][rg*4+2] + bv.z;
      float go = acc[ti][rg*4+3] + bv.w;
      const int ci = ti*4 + rg;
      float cp = FIRST ? 0.f : c[ci];
      float cn = sigf(gf)*cp + sigf(gi)*tanh_f(gg);
      float hh = sigf(go)*tanh_f(cn);
      c[ci] = cn;
      aP = fmaf(hh, WattW[j], aP);
      if (WRITEH) hF[j][col] = hh;
    }
  }
  return aP;
}

__global__ __launch_bounds__(256,2) void k_lstm5(
    const float* __restrict__ h1, const float* __restrict__ h2, const float* __restrict__ h3,
    const u16* __restrict__ Wpf, const u16* __restrict__ Wpb,
    const float4* __restrict__ Bpf, const float4* __restrict__ Bpb,
    const float* __restrict__ Watt, const float* __restrict__ batt,
    float* __restrict__ aF, float* __restrict__ aB, int gL, int N)
{
  __shared__ u16 XH[5120];
  __shared__ u16 XL[5120];
  __shared__ float hF[96][32];
  __shared__ float sAl[4][3][32];
  const int tid = threadIdx.x;
  const int l = tid & 63;
  const int rtg = __builtin_amdgcn_readfirstlane(tid >> 6);
  const int dir = (blockIdx.x >= gL) ? 1 : 0;
  const int blk = blockIdx.x - dir*gL;
  const float* sA = dir ? h3 : h1;
  const float* sC = dir ? h1 : h3;
  const u16* Wp = dir ? Wpb : Wpf;
  const float4* Bp = dir ? Bpb : Bpf;
  const float* WattW = Watt + dir*96;
  float* aD = dir ? aB : aF;
  float c[12];
  float a0, a1, a2;
  float xv[8];

  ldx_regs(sA, blk, N, tid, xv);
  stage_from_regs(xv, XH, XL, tid);
  ldx_regs(h2, blk, N, tid, xv);
  __syncthreads();

  a0 = lstm_step5<1,1>(Wp, Bp, WattW, XH, XL, hF, c, rtg, l);
  __syncthreads();
  stage_from_regs(xv, XH, XL, tid);
  restage_h(hF, XH, XL, tid);
  ldx_regs(sC, blk, N, tid, xv);
  __syncthreads();

  a1 = lstm_step5<0,1>(Wp, Bp, WattW, XH, XL, hF, c, rtg, l);
  __syncthreads();
  stage_from_regs(xv, XH, XL, tid);
  restage_h(hF, XH, XL, tid);
  __syncthreads();

  a2 = lstm_step5<0,0>(Wp, Bp, WattW, XH, XL, hF, c, rtg, l);

  a0 += __shfl_xor(a0, 32);
  a1 += __shfl_xor(a1, 32);
  a2 += __shfl_xor(a2, 32);
  if (l < 32){
    sAl[rtg][0][l] = a0;
    sAl[rtg][1][l] = a1;
    sAl[rtg][2][l] = a2;
  }
  __syncthreads();
  if (tid < 96){
    int s = tid >> 5;
    int node = tid & 31;
    int n = blk*32 + node;
    if (n < N){
      float sum = sAl[0][s][node] + sAl[1][s][node]
                + sAl[2][s][node] + sAl[3][s][node];
      int slice = dir ? (2 - s) : s;
      float v = dir ? sum : (batt[0] + sum);
      aD[(size_t)slice*N + n] = v;
    }
  }
}

// ---------------- JK softmax + xjk + Wlin + Wfc1 + leaky (16 nodes/block, round-10 proven) ----------------
__global__ __launch_bounds__(256) void k_jk(const float* __restrict__ aF, const float* __restrict__ aB,
                                            const float* __restrict__ h1, const float* __restrict__ h2,
                                            const float* __restrict__ h3,
                                            const float* __restrict__ Wlin, const float* __restrict__ blin,
                                            const float* __restrict__ Wfc1, const float* __restrict__ bfc1,
                                            float* __restrict__ vout, int N){
  __shared__ float sWl[64*65];
  __shared__ float sX[4][64];
  int tid = threadIdx.x;
  for (int idx = tid; idx < 1024; idx += 256){
    int j = idx >> 4;
    int c4 = (idx & 15) << 2;
    float4 v = *(const float4*)(Wlin + (size_t)j*64 + c4);
    sWl[j*65 + c4+0] = v.x; sWl[j*65 + c4+1] = v.y;
    sWl[j*65 + c4+2] = v.z; sWl[j*65 + c4+3] = v.w;
  }
  __syncthreads();
  int ln = tid >> 6, j = tid & 63;
  float wf1 = Wfc1[j];
  float bl = blin[j];
  for (int ib = 0; ib < 4; ++ib){
    int n = blockIdx.x*16 + ib*4 + ln;
    bool ok = n < N;
    float xj = 0.f;
    if (ok){
      float a0 = aF[n] + aB[n];
      float a1 = aF[(size_t)N + n] + aB[(size_t)N + n];
      float a2 = aF[(size_t)2*N + n] + aB[(size_t)2*N + n];
      float m = fmaxf(a0, fmaxf(a1, a2));
      float e0 = __expf(a0-m), e1 = __expf(a1-m), e2 = __expf(a2-m);
      float inv = __builtin_amdgcn_rcpf(e0+e1+e2);
      float w0 = e0*inv, w1 = e1*inv, w2 = e2*inv;
      xj = w0*h1[(size_t)n*64 + j] + w1*h2[(size_t)n*64 + j] + w2*h3[(size_t)n*64 + j];
    }
    sX[ln][j] = xj;
    __syncthreads();
    float acc = bl;
    #pragma unroll 8
    for (int cc = 0; cc < 64; ++cc) acc = fmaf(sX[ln][cc], sWl[j*65 + cc], acc);
    float r = acc * wf1;
    #pragma unroll
    for (int off = 32; off > 0; off >>= 1) r += __shfl_down(r, off);
    if (j == 0 && ok){
      float vv = r + bfc1[0];
      vout[n] = vv >= 0.f ? vv : 0.01f*vv;
    }
    __syncthreads();
  }
}

// ---------------- final dot (deterministic two-stage, f64 accum) ----------------
__global__ __launch_bounds__(256) void k_final1(const float* __restrict__ w, const float* __restrict__ v,
                                                double* __restrict__ part, int N){
  __shared__ double sd[256];
  int tid = threadIdx.x;
  double a = 0.0;
  for (int i = blockIdx.x*256 + tid; i < N; i += 256*256)
    a += (double)(w[i] * v[i]);
  sd[tid] = a; __syncthreads();
  for (int off = 128; off > 0; off >>= 1){
    if (tid < off) sd[tid] += sd[tid + off];
    __syncthreads();
  }
  if (tid == 0) part[blockIdx.x] = sd[0];
}

__global__ __launch_bounds__(256) void k_final2(const double* __restrict__ part, const float* __restrict__ bfc2,
                                                float* __restrict__ out){
  __shared__ double sd[256];
  int tid = threadIdx.x;
  sd[tid] = part[tid]; __syncthreads();
  for (int off = 128; off > 0; off >>= 1){
    if (tid < off) sd[tid] += sd[tid + off];
    __syncthreads();
  }
  if (tid == 0) out[0] = (float)(sd[0] + (double)bfc2[0]);
}

// ---------------- host ----------------
extern "C" void kernel_launch(void* const* d_in, const int* in_sizes, int n_in,
                              void* d_out, int out_size, void* d_ws, size_t ws_size,
                              hipStream_t stream){
  const float* x    = (const float*)d_in[0];
  const int*   ei   = (const int*)d_in[1];
  const float* W0a  = (const float*)d_in[2];
  const float* b0a  = (const float*)d_in[3];
  const float* W0b  = (const float*)d_in[4];
  const float* b0b  = (const float*)d_in[5];
  const float* W1a  = (const float*)d_in[6];
  const float* b1a  = (const float*)d_in[7];
  const float* W1b  = (const float*)d_in[8];
  const float* b1b  = (const float*)d_in[9];
  const float* W2a  = (const float*)d_in[10];
  const float* b2a  = (const float*)d_in[11];
  const float* W2b  = (const float*)d_in[12];
  const float* b2b  = (const float*)d_in[13];
  const float* Wih_f = (const float*)d_in[14];
  const float* Whh_f = (const float*)d_in[15];
  const float* bih_f = (const float*)d_in[16];
  const float* bhh_f = (const float*)d_in[17];
  const float* Wih_b = (const float*)d_in[18];
  const float* Whh_b = (const float*)d_in[19];
  const float* bih_b = (const float*)d_in[20];
  const float* bhh_b = (const float*)d_in[21];
  const float* Watt = (const float*)d_in[22];
  const float* batt = (const float*)d_in[23];
  const float* Wlin = (const float*)d_in[24];
  const float* blin = (const float*)d_in[25];
  const float* Wfc1 = (const float*)d_in[26];
  const float* bfc1 = (const float*)d_in[27];
  const float* Wfc2 = (const float*)d_in[28];
  const float* bfc2 = (const float*)d_in[29];
  float* out = (float*)d_out;

  const int N = in_sizes[0] / 128;
  const int E = in_sizes[1] / 2;
  const int* src = ei;
  const int* dst = ei + E;

  uint8_t* w8 = (uint8_t*)d_ws;
  size_t off = 0;
  auto alloc = [&](size_t bytes) -> void* {
    void* p = w8 + off;
    off = (off + bytes + 255) & ~(size_t)255;
    return p;
  };
  int*    deg    = (int*)   alloc((size_t)N*4);
  int*    fill   = (int*)   alloc((size_t)N*4);
  int*    indptr = (int*)   alloc(((size_t)N+1)*4);
  int*    col    = (int*)   alloc((size_t)E*4);
  int*    bsum   = (int*)   alloc(2048);
  int*    boffs  = (int*)   alloc(2048);
  float*  h1     = (float*) alloc((size_t)N*64*4);
  float*  h2     = (float*) alloc((size_t)N*64*4);
  float*  h3     = (float*) alloc((size_t)N*64*4);
  float*  aF     = (float*) alloc((size_t)3*N*4);
  float*  aB     = (float*) alloc((size_t)3*N*4);
  float*  vbuf   = (float*) alloc((size_t)N*4);
  double* part   = (double*)alloc(256*8);
  u16*    Wpf    = (u16*)   alloc((size_t)10*12*64*8*2);
  u16*    Wpb    = (u16*)   alloc((size_t)10*12*64*8*2);
  float4* Bpf    = (float4*)alloc((size_t)96*16);
  float4* Bpb    = (float4*)alloc((size_t)96*16);
  u16*    Wg0a   = (u16*)   alloc((size_t)128*128*2);
  u16*    Wg0b   = (u16*)   alloc((size_t)64*128*2);
  u16*    Wg1a   = (u16*)   alloc((size_t)64*128*2);
  u16*    Wg1b   = (u16*)   alloc((size_t)64*128*2);
  u16*    Wg2a   = (u16*)   alloc((size_t)64*128*2);
  u16*    Wg2b   = (u16*)   alloc((size_t)64*128*2);
  float*  P      = (float*) alloc((size_t)N*192*4);
  if (off > ws_size) return;
  float* ybuf = P;
  float* zbuf = P + (size_t)N*64;

  hipMemsetAsync(deg,  0, (size_t)N*4, stream);
  hipMemsetAsync(fill, 0, (size_t)N*4, stream);

  int gE = (E + 255) / 256;
  int nb1 = (N + 255) / 256;
  int gG = (N + 63) / 64;
  int gA = (N + 15) / 16;
  int gL = (N + 31) / 32;

  // weight prepack (independent of CSR)
  k_packW1<<<240, 256, 0, stream>>>(Wih_f, Whh_f, Wpf);
  k_packW1<<<240, 256, 0, stream>>>(Wih_b, Whh_b, Wpb);
  k_packB<<<1, 128, 0, stream>>>(bih_f, bhh_f, Bpf);
  k_packB<<<1, 128, 0, stream>>>(bih_b, bhh_b, Bpb);
  k_packG<<<64, 256, 0, stream>>>(W0a, Wg0a, 128);
  k_packG<<<32, 256, 0, stream>>>(W0b, Wg0b, 64);
  k_packG<<<32, 256, 0, stream>>>(W1a, Wg1a, 64);
  k_packG<<<32, 256, 0, stream>>>(W1b, Wg1b, 64);
  k_packG<<<32, 256, 0, stream>>>(W2a, Wg2a, 64);
  k_packG<<<32, 256, 0, stream>>>(W2b, Wg2b, 64);

  k_deg  <<<gE, 256, 0, stream>>>(dst, deg, E);
  k_scan1<<<nb1, 256, 0, stream>>>(deg, indptr, bsum, N);
  k_scan2<<<1, 512, 0, stream>>>(bsum, boffs, indptr, nb1, N);
  k_scan3<<<nb1, 256, 0, stream>>>(indptr, boffs, N);
  k_fill <<<gE, 256, 0, stream>>>(src, dst, indptr, fill, col, E);

  // ---- GIN layer 0 (transform-first: (x+aggX)@W = y+aggY) ----
  k_mfgemm<128,0><<<gG, 256, 0, stream>>>(x, Wg0a, nullptr, ybuf, N);
  k_agg<64><<<gA, 256, 0, stream>>>(ybuf, indptr, col, b0a, zbuf, N);
  k_mfgemm<64,1><<<gG, 256, 0, stream>>>(zbuf, Wg0b, b0b, h1, N);
  // ---- GIN layer 1 ----
  k_mfgemm<64,0><<<gG, 256, 0, stream>>>(h1, Wg1a, nullptr, ybuf, N);
  k_agg<64><<<gA, 256, 0, stream>>>(ybuf, indptr, col, b1a, zbuf, N);
  k_mfgemm<64,1><<<gG, 256, 0, stream>>>(zbuf, Wg1b, b1b, h2, N);
  // ---- GIN layer 2 ----
  k_mfgemm<64,0><<<gG, 256, 0, stream>>>(h2, Wg2a, nullptr, ybuf, N);
  k_agg<64><<<gA, 256, 0, stream>>>(ybuf, indptr, col, b2a, zbuf, N);
  k_mfgemm<64,1><<<gG, 256, 0, stream>>>(zbuf, Wg2b, b2b, h3, N);

  // ---- LSTM: both directions in one dispatch ----
  k_lstm5<<<2*gL, 256, 0, stream>>>(h1, h2, h3, Wpf, Wpb, Bpf, Bpb, Watt, batt,
                                    aF, aB, gL, N);

  // ---- JK attention + linear + fc1 + leaky ----
  k_jk<<<gA, 256, 0, stream>>>(aF, aB, h1, h2, h3, Wlin, blin, Wfc1, bfc1, vbuf, N);

  // ---- final dot ----
  k_final1<<<256, 256, 0, stream>>>(Wfc2, vbuf, part, N);
  k_final2<<<1, 256, 0, stream>>>(part, bfc2, out);
}

// Round 14
// 660.913 us; speedup vs baseline: 1.2764x; 1.0538x over previous
//
#include <hip/hip_runtime.h>
#include <stdint.h>

typedef unsigned short u16;
typedef unsigned int u32;
using short8 = __attribute__((ext_vector_type(8))) short;
using f32x16 = __attribute__((ext_vector_type(16))) float;

__device__ __forceinline__ float sigf(float x){
  return __builtin_amdgcn_rcpf(1.0f + __expf(-x));
}
__device__ __forceinline__ float tanh_f(float x){
  return 1.0f - 2.0f*__builtin_amdgcn_rcpf(1.0f + __expf(2.0f*x));
}
__device__ __forceinline__ u16 f2bf(float f){
  u32 u = __float_as_uint(f);
  u += 0x7FFFu + ((u>>16)&1u);
  return (u16)(u>>16);
}
__device__ __forceinline__ float bf2f(u16 h){ return __uint_as_float(((u32)h)<<16); }

// ---------------- CSR build ----------------
__global__ void k_deg(const int* __restrict__ dst, int* __restrict__ deg, int E){
  int i = blockIdx.x*256 + threadIdx.x;
  if (i < E) atomicAdd(&deg[dst[i]], 1);
}

__global__ __launch_bounds__(256) void k_scan1(const int* __restrict__ deg, int* __restrict__ indptr,
                                               int* __restrict__ bsum, int N){
  __shared__ int s[256];
  int tid = threadIdx.x;
  int i = blockIdx.x*256 + tid;
  int v = (i < N) ? deg[i] : 0;
  s[tid] = v; __syncthreads();
  for (int off=1; off<256; off<<=1){
    int t = (tid>=off) ? s[tid-off] : 0;
    __syncthreads();
    s[tid] += t;
    __syncthreads();
  }
  if (i < N) indptr[i] = s[tid] - v;
  if (tid == 255) bsum[blockIdx.x] = s[255];
}

__global__ __launch_bounds__(512) void k_scan2(const int* __restrict__ bsum, int* __restrict__ boffs,
                                               int* __restrict__ indptr, int nb, int N){
  __shared__ int s[512];
  int tid = threadIdx.x;
  int v = (tid < nb) ? bsum[tid] : 0;
  s[tid] = v; __syncthreads();
  for (int off=1; off<512; off<<=1){
    int t = (tid>=off) ? s[tid-off] : 0;
    __syncthreads();
    s[tid] += t;
    __syncthreads();
  }
  boffs[tid] = s[tid] - v;
  if (tid == nb-1) indptr[N] = s[tid];
}

__global__ __launch_bounds__(256) void k_scan3(int* __restrict__ indptr, const int* __restrict__ boffs, int N){
  int i = blockIdx.x*256 + threadIdx.x;
  if (i < N) indptr[i] += boffs[blockIdx.x];
}

__global__ void k_fill(const int* __restrict__ src, const int* __restrict__ dst,
                       const int* __restrict__ indptr, int* __restrict__ fill,
                       int* __restrict__ col, int E){
  int i = blockIdx.x*256 + threadIdx.x;
  if (i < E){
    int d = dst[i];
    int r = atomicAdd(&fill[d], 1);
    col[indptr[d] + r] = src[i];
  }
}

// ---------------- aggregation (proven): z[n] = relu( y[n] + sum y[src] + b ) ----------------
template<int F>
__global__ __launch_bounds__(256) void k_agg(const float* __restrict__ y, const int* __restrict__ indptr,
                                             const int* __restrict__ col, const float* __restrict__ bias,
                                             float* __restrict__ z, int N){
  constexpr int TPN = F/4;
  constexpr int NPB = 256/TPN;
  int n = blockIdx.x*NPB + threadIdx.x/TPN;
  int lane = threadIdx.x % TPN;
  if (n >= N) return;
  const float4* hv = (const float4*)y;
  float4 acc = hv[(size_t)n*TPN + lane];
  int s = indptr[n], e = indptr[n+1];
  int p = s;
  for (; p + 8 <= e; p += 8){
    int c8[8];
    #pragma unroll
    for (int i=0;i<8;++i) c8[i] = col[p+i];
    #pragma unroll
    for (int i=0;i<8;++i){
      float4 x = hv[(size_t)c8[i]*TPN + lane];
      acc.x += x.x; acc.y += x.y; acc.z += x.z; acc.w += x.w;
    }
  }
  for (; p < e; ++p){
    float4 x = hv[(size_t)col[p]*TPN + lane];
    acc.x += x.x; acc.y += x.y; acc.z += x.z; acc.w += x.w;
  }
  float4 b4 = ((const float4*)bias)[lane];
  acc.x = fmaxf(acc.x + b4.x, 0.f);
  acc.y = fmaxf(acc.y + b4.y, 0.f);
  acc.z = fmaxf(acc.z + b4.z, 0.f);
  acc.w = fmaxf(acc.w + b4.w, 0.f);
  ((float4*)z)[(size_t)n*TPN + lane] = acc;
}

// ---------------- GIN GEMM weight prepack: frag-linear bf16 hi/lo ----------------
__global__ __launch_bounds__(256) void k_packG(const float* __restrict__ W, u16* __restrict__ Wg, int K){
  int idx = blockIdx.x*256 + threadIdx.x;
  if (idx >= K*128) return;
  int i  = idx & 7;
  int l  = (idx>>3) & 63;
  int p  = (idx>>9) & 1;
  int rt = (idx>>10) & 1;
  int kt = idx >> 11;
  int j  = rt*32 + (l & 31);
  int k  = kt*16 + ((l>>5)<<3) + i;
  float v = W[(size_t)j*K + k];
  u16 h = f2bf(v);
  Wg[idx] = p ? f2bf(v - bf2f(h)) : h;
}

__device__ __forceinline__ void cvt8p(const float (&v)[8], u32 (&hw)[4], u32 (&lw)[4]){
  #pragma unroll
  for (int i=0;i<4;++i){
    u16 h0=f2bf(v[2*i]),   h1=f2bf(v[2*i+1]);
    u16 l0=f2bf(v[2*i]-bf2f(h0)), l1=f2bf(v[2*i+1]-bf2f(h1));
    hw[i]= (u32)h0 | ((u32)h1<<16);
    lw[i]= (u32)l0 | ((u32)l1<<16);
  }
}

// stage 8 f32 values into frag-linear hi/lo planes (node,kc addressing)
__device__ __forceinline__ void stageG(const float (&v)[8], u16* __restrict__ BH, u16* __restrict__ BL,
                                       int node, int kc, int NKT){
  u32 hw[4], lw[4];
  cvt8p(v, hw, lw);
  int kt = kc >> 1, h2 = kc & 1;
  int sl = (((h2<<5) | (node&31)) ^ (kc & 7));
  int addr = (((node>>5)*NKT + kt)<<9) + (sl<<3);
  *(uint4*)(BH + addr) = make_uint4(hw[0],hw[1],hw[2],hw[3]);
  *(uint4*)(BL + addr) = make_uint4(lw[0],lw[1],lw[2],lw[3]);
}

// ---------------- MFMA GEMM (single): out[n][j] = act( A@W^T + b ) ----------------
template<int K, int ACT>
__global__ __launch_bounds__(256,2) void k_mfgemm(const float* __restrict__ A, const u16* __restrict__ Wg,
                                                  const float* __restrict__ bias, float* __restrict__ out,
                                                  int N){
  constexpr int NKT = K/16;
  __shared__ u16 BH[2*NKT*512];
  __shared__ u16 BL[2*NKT*512];
  const int tid = threadIdx.x;
  const int l = tid & 63;
  const int w = __builtin_amdgcn_readfirstlane(tid >> 6);
  const int rt = w >> 1, nt = w & 1;
  const int nb = blockIdx.x * 64;
  const int hi = l >> 5;

  for (int u = tid; u < 64*(K/8); u += 256){
    int node = u / (K/8);
    int kc = u % (K/8);
    int n = nb + node;
    float v[8];
    if (n < N){
      const float4* s4 = (const float4*)(A + (size_t)n*K + kc*8);
      float4 a = s4[0], b = s4[1];
      v[0]=a.x; v[1]=a.y; v[2]=a.z; v[3]=a.w; v[4]=b.x; v[5]=b.y; v[6]=b.z; v[7]=b.w;
    } else {
      #pragma unroll
      for (int i=0;i<8;++i) v[i]=0.f;
    }
    stageG(v, BH, BL, node, kc, NKT);
  }
  __syncthreads();

  f32x16 acc;
  #pragma unroll
  for (int r=0;r<16;++r) acc[r] = 0.f;
  const u16* wbase = Wg + ((size_t)rt<<10) + ((size_t)l<<3);
  #pragma unroll
  for (int kt = 0; kt < NKT; ++kt){
    const u16* wk = wbase + (size_t)kt*2048;
    short8 Ah = *(const short8*)(wk);
    short8 Al = *(const short8*)(wk + 512);
    int sl = l ^ (((kt<<1) + hi) & 7);
    int baddr = ((nt*NKT + kt)<<9) + (sl<<3);
    short8 Bh = *(const short8*)(BH + baddr);
    short8 Bl = *(const short8*)(BL + baddr);
    acc = __builtin_amdgcn_mfma_f32_32x32x16_bf16(Ah, Bh, acc, 0,0,0);
    acc = __builtin_amdgcn_mfma_f32_32x32x16_bf16(Ah, Bl, acc, 0,0,0);
    acc = __builtin_amdgcn_mfma_f32_32x32x16_bf16(Al, Bh, acc, 0,0,0);
  }

  const int col = l & 31;
  const int n = nb + nt*32 + col;
  if (n < N){
    #pragma unroll
    for (int g = 0; g < 4; ++g){
      const int j0 = rt*32 + 8*g + 4*hi;
      float4 b4 = bias ? *(const float4*)(bias + j0) : make_float4(0.f,0.f,0.f,0.f);
      float4 o;
      o.x = acc[4*g+0] + b4.x;
      o.y = acc[4*g+1] + b4.y;
      o.z = acc[4*g+2] + b4.z;
      o.w = acc[4*g+3] + b4.w;
      if (ACT){
        o.x = fmaxf(o.x, 0.f); o.y = fmaxf(o.y, 0.f);
        o.z = fmaxf(o.z, 0.f); o.w = fmaxf(o.w, 0.f);
      }
      *(float4*)(out + (size_t)n*64 + j0) = o;
    }
  }
}

// ---------------- fused pair: H = relu(Z@Wb+bb) (store) ; Y = H@Wa (store) ----------------
__global__ __launch_bounds__(256,2) void k_mfgemm2(const float* __restrict__ Z, const u16* __restrict__ Wgb,
                                                   const float* __restrict__ bb, const u16* __restrict__ Wga,
                                                   float* __restrict__ Hout, float* __restrict__ Yout,
                                                   int N){
  __shared__ u16 BH[4096];
  __shared__ u16 BL[4096];
  __shared__ float hX[64][68];
  const int tid = threadIdx.x;
  const int l = tid & 63;
  const int w = __builtin_amdgcn_readfirstlane(tid >> 6);
  const int rt = w >> 1, nt = w & 1;
  const int nb = blockIdx.x * 64;
  const int hi = l >> 5;
  const int col = l & 31;
  const int n = nb + nt*32 + col;

  // phase 1: stage Z
  for (int u = tid; u < 512; u += 256){
    int node = u >> 3;
    int kc = u & 7;
    int nn = nb + node;
    float v[8];
    if (nn < N){
      const float4* s4 = (const float4*)(Z + (size_t)nn*64 + kc*8);
      float4 a = s4[0], b = s4[1];
      v[0]=a.x; v[1]=a.y; v[2]=a.z; v[3]=a.w; v[4]=b.x; v[5]=b.y; v[6]=b.z; v[7]=b.w;
    } else {
      #pragma unroll
      for (int i=0;i<8;++i) v[i]=0.f;
    }
    stageG(v, BH, BL, node, kc, 4);
  }
  __syncthreads();

  f32x16 acc;
  #pragma unroll
  for (int r=0;r<16;++r) acc[r] = 0.f;
  {
    const u16* wbase = Wgb + ((size_t)rt<<10) + ((size_t)l<<3);
    #pragma unroll
    for (int kt = 0; kt < 4; ++kt){
      const u16* wk = wbase + (size_t)kt*2048;
      short8 Ah = *(const short8*)(wk);
      short8 Al = *(const short8*)(wk + 512);
      int sl = l ^ (((kt<<1) + hi) & 7);
      int baddr = ((nt*4 + kt)<<9) + (sl<<3);
      short8 Bh = *(const short8*)(BH + baddr);
      short8 Bl = *(const short8*)(BL + baddr);
      acc = __builtin_amdgcn_mfma_f32_32x32x16_bf16(Ah, Bh, acc, 0,0,0);
      acc = __builtin_amdgcn_mfma_f32_32x32x16_bf16(Ah, Bl, acc, 0,0,0);
      acc = __builtin_amdgcn_mfma_f32_32x32x16_bf16(Al, Bh, acc, 0,0,0);
    }
  }
  // epilogue 1: bias+relu, write H global + hX
  {
    const int node = nt*32 + col;
    #pragma unroll
    for (int g = 0; g < 4; ++g){
      const int j0 = rt*32 + 8*g + 4*hi;
      float4 b4 = *(const float4*)(bb + j0);
      float4 o;
      o.x = fmaxf(acc[4*g+0] + b4.x, 0.f);
      o.y = fmaxf(acc[4*g+1] + b4.y, 0.f);
      o.z = fmaxf(acc[4*g+2] + b4.z, 0.f);
      o.w = fmaxf(acc[4*g+3] + b4.w, 0.f);
      if (n < N) *(float4*)(Hout + (size_t)n*64 + j0) = o;
      *(float4*)(&hX[node][j0]) = o;
    }
  }
  __syncthreads();

  // phase 2: restage H from hX
  for (int u = tid; u < 512; u += 256){
    int node = u >> 3;
    int kc = u & 7;
    float v[8];
    #pragma unroll
    for (int i=0;i<8;++i) v[i] = hX[node][kc*8 + i];
    stageG(v, BH, BL, node, kc, 4);
  }
  __syncthreads();

  #pragma unroll
  for (int r=0;r<16;++r) acc[r] = 0.f;
  {
    const u16* wbase = Wga + ((size_t)rt<<10) + ((size_t)l<<3);
    #pragma unroll
    for (int kt = 0; kt < 4; ++kt){
      const u16* wk = wbase + (size_t)kt*2048;
      short8 Ah = *(const short8*)(wk);
      short8 Al = *(const short8*)(wk + 512);
      int sl = l ^ (((kt<<1) + hi) & 7);
      int baddr = ((nt*4 + kt)<<9) + (sl<<3);
      short8 Bh = *(const short8*)(BH + baddr);
      short8 Bl = *(const short8*)(BL + baddr);
      acc = __builtin_amdgcn_mfma_f32_32x32x16_bf16(Ah, Bh, acc, 0,0,0);
      acc = __builtin_amdgcn_mfma_f32_32x32x16_bf16(Ah, Bl, acc, 0,0,0);
      acc = __builtin_amdgcn_mfma_f32_32x32x16_bf16(Al, Bh, acc, 0,0,0);
    }
  }
  if (n < N){
    #pragma unroll
    for (int g = 0; g < 4; ++g){
      const int j0 = rt*32 + 8*g + 4*hi;
      float4 o;
      o.x = acc[4*g+0]; o.y = acc[4*g+1]; o.z = acc[4*g+2]; o.w = acc[4*g+3];
      *(float4*)(Yout + (size_t)n*64 + j0) = o;
    }
  }
}

// ---------------- LSTM weight prepack: fragment-linear bf16, SINGLE plane ----------------
__global__ __launch_bounds__(256) void k_packW1(const float* __restrict__ Wih, const float* __restrict__ Whh,
                                                u16* __restrict__ Wp){
  int idx = blockIdx.x*256 + threadIdx.x;
  if (idx >= 10*12*64*8) return;
  int i  = idx & 7;
  int l  = (idx>>3) & 63;
  int rt = (idx>>9) % 12;
  int kt = (idx>>9) / 12;
  int r  = rt*32 + (l & 31);
  int j  = r >> 2, g = r & 3;
  int row = g*96 + j;
  int k  = kt*16 + ((l>>5)<<3) + i;
  float v = (k < 64) ? Wih[row*64 + k] : Whh[row*96 + (k-64)];
  Wp[idx] = f2bf(v);
}

__global__ __launch_bounds__(128) void k_packB(const float* __restrict__ bih, const float* __restrict__ bhh,
                                               float4* __restrict__ Bp){
  int j = blockIdx.x*128 + threadIdx.x;
  if (j >= 96) return;
  Bp[j] = make_float4(bih[j]+bhh[j], bih[96+j]+bhh[96+j],
                      bih[192+j]+bhh[192+j], bih[288+j]+bhh[288+j]);
}

// ---------------- MFMA LSTM v5b (proven 215 us) ----------------
__device__ __forceinline__ void ldx_regs(const float* __restrict__ seq, int blk, int N, int tid,
                                         float (&v)[8]){
  int node = tid >> 3;
  int kc = tid & 7;
  int n = blk*32 + node;
  if (n < N){
    const float4* s4 = (const float4*)(seq + (size_t)n*64 + kc*8);
    float4 a = s4[0], b = s4[1];
    v[0]=a.x; v[1]=a.y; v[2]=a.z; v[3]=a.w; v[4]=b.x; v[5]=b.y; v[6]=b.z; v[7]=b.w;
  } else {
    #pragma unroll
    for (int i=0;i<8;++i) v[i]=0.f;
  }
}

__device__ __forceinline__ void stage_from_regs(const float (&v)[8], u16* __restrict__ XH,
                                                u16* __restrict__ XL, int tid){
  int node = tid >> 3;
  int kc = tid & 7;
  u32 hw[4], lw[4];
  cvt8p(v, hw, lw);
  int kt = kc >> 1, hi = kc & 1;
  int sl = (((hi<<5) | node) ^ (kc & 7));
  int addr = (kt<<9) + (sl<<3);
  *(uint4*)(XH + addr) = make_uint4(hw[0],hw[1],hw[2],hw[3]);
  *(uint4*)(XL + addr) = make_uint4(lw[0],lw[1],lw[2],lw[3]);
}

__device__ __forceinline__ void restage_h(const float (*hF)[32], u16* __restrict__ XH,
                                          u16* __restrict__ XL, int tid){
  int node = tid & 31;
  #pragma unroll
  for (int q = 0; q < 2; ++q){
    int cc = (tid >> 5) + q*8;
    if (cc < 12){
      int kth = cc >> 1, hi = cc & 1;
      int ktG = kth + 4;
      float v[8];
      #pragma unroll
      for (int i=0;i<8;++i) v[i] = hF[cc*8 + i][node];
      u32 hw[4], lw[4];
      cvt8p(v, hw, lw);
      int sl = (((hi<<5) | node) ^ ((2*ktG + hi) & 7));
      int addr = (ktG<<9) + (sl<<3);
      *(uint4*)(XH + addr) = make_uint4(hw[0],hw[1],hw[2],hw[3]);
      *(uint4*)(XL + addr) = make_uint4(lw[0],lw[1],lw[2],lw[3]);
    }
  }
}

template<int FIRST, int WRITEH>
__device__ __forceinline__ float lstm_step5(const u16* __restrict__ Wp,
    const float4* __restrict__ Bp, const float* __restrict__ WattW,
    const u16* __restrict__ XH, const u16* __restrict__ XL, float (*hF)[32],
    float (&c)[12], int rtg, int l)
{
  constexpr int NKT = FIRST ? 4 : 10;
  const int hi = l >> 5;
  const int col = l & 31;
  f32x16 acc[3];
  #pragma unroll
  for (int t=0;t<3;++t)
    #pragma unroll
    for (int r=0;r<16;++r) acc[t][r] = 0.f;

  const u16* wbase = Wp + (size_t)(rtg*3)*512 + ((size_t)l<<3);
  #pragma unroll
  for (int kt = 0; kt < NKT; ++kt){
    const u16* wk = wbase + (size_t)kt*6144;
    short8 A0 = *(const short8*)(wk);
    short8 A1 = *(const short8*)(wk + 512);
    short8 A2 = *(const short8*)(wk + 1024);
    int sl = l ^ (((kt<<1) + hi) & 7);
    int baddr = (kt<<9) + (sl<<3);
    short8 Bh = *(const short8*)(XH + baddr);
    short8 Bl = *(const short8*)(XL + baddr);
    __builtin_amdgcn_s_setprio(1);
    acc[0] = __builtin_amdgcn_mfma_f32_32x32x16_bf16(A0, Bh, acc[0], 0,0,0);
    acc[1] = __builtin_amdgcn_mfma_f32_32x32x16_bf16(A1, Bh, acc[1], 0,0,0);
    acc[2] = __builtin_amdgcn_mfma_f32_32x32x16_bf16(A2, Bh, acc[2], 0,0,0);
    acc[0] = __builtin_amdgcn_mfma_f32_32x32x16_bf16(A0, Bl, acc[0], 0,0,0);
    acc[1] = __builtin_amdgcn_mfma_f32_32x32x16_bf16(A1, Bl, acc[1], 0,0,0);
    acc[2] = __builtin_amdgcn_mfma_f32_32x32x16_bf16(A2, Bl, acc[2], 0,0,0);
    __builtin_amdgcn_s_setprio(0);
  }

  float aP = 0.f;
  #pragma unroll
  for (int ti=0;ti<3;++ti){
    #pragma unroll
    for (int rg=0; rg<4; ++rg){
      const int j = (rtg*3+ti)*8 + 2*rg + hi;
      float4 bv = Bp[j];
      float gi = acc[ti][rg*4+0] + bv.x;
      float gf = acc[ti][rg*4+1] + bv.y;
      float gg = acc[ti][rg*4+2] + bv.z;
      float go = acc[ti][rg*4+3] + bv.w;
      const int ci = ti*4 + rg;
      float cp = FIRST ? 0.f : c[ci];
      float cn = sigf(gf)*cp + sigf(gi)*tanh_f(gg);
      float hh = sigf(go)*tanh_f(cn);
      c[ci] = cn;
      aP = fmaf(hh, WattW[j], aP);
      if (WRITEH) hF[j][col] = hh;
    }
  }
  return aP;
}

__global__ __launch_bounds__(256,2) void k_lstm5(
    const float* __restrict__ h1, const float* __restrict__ h2, const float* __restrict__ h3,
    const u16* __restrict__ Wpf, const u16* __restrict__ Wpb,
    const float4* __restrict__ Bpf, const float4* __restrict__ Bpb,
    const float* __restrict__ Watt, const float* __restrict__ batt,
    float* __restrict__ aF, float* __restrict__ aB, int gL, int N)
{
  __shared__ u16 XH[5120];
  __shared__ u16 XL[5120];
  __shared__ float hF[96][32];
  __shared__ float sAl[4][3][32];
  const int tid = threadIdx.x;
  const int l = tid & 63;
  const int rtg = __builtin_amdgcn_readfirstlane(tid >> 6);
  const int dir = (blockIdx.x >= gL) ? 1 : 0;
  const int blk = blockIdx.x - dir*gL;
  const float* sA = dir ? h3 : h1;
  const float* sC = dir ? h1 : h3;
  const u16* Wp = dir ? Wpb : Wpf;
  const float4* Bp = dir ? Bpb : Bpf;
  const float* WattW = Watt + dir*96;
  float* aD = dir ? aB : aF;
  float c[12];
  float a0, a1, a2;
  float xv[8];

  ldx_regs(sA, blk, N, tid, xv);
  stage_from_regs(xv, XH, XL, tid);
  ldx_regs(h2, blk, N, tid, xv);
  __syncthreads();

  a0 = lstm_step5<1,1>(Wp, Bp, WattW, XH, XL, hF, c, rtg, l);
  __syncthreads();
  stage_from_regs(xv, XH, XL, tid);
  restage_h(hF, XH, XL, tid);
  ldx_regs(sC, blk, N, tid, xv);
  __syncthreads();

  a1 = lstm_step5<0,1>(Wp, Bp, WattW, XH, XL, hF, c, rtg, l);
  __syncthreads();
  stage_from_regs(xv, XH, XL, tid);
  restage_h(hF, XH, XL, tid);
  __syncthreads();

  a2 = lstm_step5<0,0>(Wp, Bp, WattW, XH, XL, hF, c, rtg, l);

  a0 += __shfl_xor(a0, 32);
  a1 += __shfl_xor(a1, 32);
  a2 += __shfl_xor(a2, 32);
  if (l < 32){
    sAl[rtg][0][l] = a0;
    sAl[rtg][1][l] = a1;
    sAl[rtg][2][l] = a2;
  }
  __syncthreads();
  if (tid < 96){
    int s = tid >> 5;
    int node = tid & 31;
    int n = blk*32 + node;
    if (n < N){
      float sum = sAl[0][s][node] + sAl[1][s][node]
                + sAl[2][s][node] + sAl[3][s][node];
      int slice = dir ? (2 - s) : s;
      float v = dir ? sum : (batt[0] + sum);
      aD[(size_t)slice*N + n] = v;
    }
  }
}

// ---------------- JK via MFMA: softmax + xjk + Wlin + fc1-dot + leaky ----------------
__global__ __launch_bounds__(256,2) void k_jk2(const float* __restrict__ aF, const float* __restrict__ aB,
                                               const float* __restrict__ h1, const float* __restrict__ h2,
                                               const float* __restrict__ h3,
                                               const u16* __restrict__ WgL, const float* __restrict__ blin,
                                               const float* __restrict__ Wfc1, const float* __restrict__ bfc1,
                                               float* __restrict__ vout, int N){
  __shared__ u16 BH[4096];
  __shared__ u16 BL[4096];
  __shared__ float sP[4][32];
  const int tid = threadIdx.x;
  const int l = tid & 63;
  const int w = __builtin_amdgcn_readfirstlane(tid >> 6);
  const int rt = w >> 1, nt = w & 1;
  const int nb = blockIdx.x * 64;
  const int hi = l >> 5;
  const int col = l & 31;

  // stage xjk (softmax-weighted combo) as bf16 hi/lo frags
  for (int u = tid; u < 512; u += 256){
    int node = u >> 3;
    int kc = u & 7;
    int n = nb + node;
    float v[8];
    if (n < N){
      float a0 = aF[n] + aB[n];
      float a1 = aF[(size_t)N + n] + aB[(size_t)N + n];
      float a2 = aF[(size_t)2*N + n] + aB[(size_t)2*N + n];
      float m = fmaxf(a0, fmaxf(a1, a2));
      float e0 = __expf(a0-m), e1 = __expf(a1-m), e2 = __expf(a2-m);
      float inv = __builtin_amdgcn_rcpf(e0+e1+e2);
      float w0 = e0*inv, w1 = e1*inv, w2 = e2*inv;
      const float4* p1 = (const float4*)(h1 + (size_t)n*64 + kc*8);
      const float4* p2 = (const float4*)(h2 + (size_t)n*64 + kc*8);
      const float4* p3 = (const float4*)(h3 + (size_t)n*64 + kc*8);
      #pragma unroll
      for (int q=0;q<2;++q){
        float4 x1 = p1[q], x2 = p2[q], x3 = p3[q];
        v[4*q+0] = w0*x1.x + w1*x2.x + w2*x3.x;
        v[4*q+1] = w0*x1.y + w1*x2.y + w2*x3.y;
        v[4*q+2] = w0*x1.z + w1*x2.z + w2*x3.z;
        v[4*q+3] = w0*x1.w + w1*x2.w + w2*x3.w;
      }
    } else {
      #pragma unroll
      for (int i=0;i<8;++i) v[i]=0.f;
    }
    stageG(v, BH, BL, node, kc, 4);
  }
  __syncthreads();

  f32x16 acc;
  #pragma unroll
  for (int r=0;r<16;++r) acc[r] = 0.f;
  const u16* wbase = WgL + ((size_t)rt<<10) + ((size_t)l<<3);
  #pragma unroll
  for (int kt = 0; kt < 4; ++kt){
    const u16* wk = wbase + (size_t)kt*2048;
    short8 Ah = *(const short8*)(wk);
    short8 Al = *(const short8*)(wk + 512);
    int sl = l ^ (((kt<<1) + hi) & 7);
    int baddr = ((nt*4 + kt)<<9) + (sl<<3);
    short8 Bh = *(const short8*)(BH + baddr);
    short8 Bl = *(const short8*)(BL + baddr);
    acc = __builtin_amdgcn_mfma_f32_32x32x16_bf16(Ah, Bh, acc, 0,0,0);
    acc = __builtin_amdgcn_mfma_f32_32x32x16_bf16(Ah, Bl, acc, 0,0,0);
    acc = __builtin_amdgcn_mfma_f32_32x32x16_bf16(Al, Bh, acc, 0,0,0);
  }

  // fc1 dot: partial over this lane's 16 j's
  float p = 0.f;
  #pragma unroll
  for (int g = 0; g < 4; ++g){
    #pragma unroll
    for (int rg = 0; rg < 4; ++rg){
      const int j = rt*32 + 8*g + 4*hi + rg;
      p += (acc[4*g+rg] + blin[j]) * Wfc1[j];
    }
  }
  p += __shfl_xor(p, 32);
  if (l < 32) sP[w][l] = p;
  __syncthreads();
  if (tid < 64){
    int node = tid;
    int nt2 = node >> 5, c2 = node & 31;
    int n = nb + node;
    if (n < N){
      float t = sP[nt2][c2] + sP[2+nt2][c2] + bfc1[0];
      vout[n] = t >= 0.f ? t : 0.01f*t;
    }
  }
}

// ---------------- final dot (deterministic two-stage, f64 accum) ----------------
__global__ __launch_bounds__(256) void k_final1(const float* __restrict__ w, const float* __restrict__ v,
                                                double* __restrict__ part, int N){
  __shared__ double sd[256];
  int tid = threadIdx.x;
  double a = 0.0;
  for (int i = blockIdx.x*256 + tid; i < N; i += 256*256)
    a += (double)(w[i] * v[i]);
  sd[tid] = a; __syncthreads();
  for (int off = 128; off > 0; off >>= 1){
    if (tid < off) sd[tid] += sd[tid + off];
    __syncthreads();
  }
  if (tid == 0) part[blockIdx.x] = sd[0];
}

__global__ __launch_bounds__(256) void k_final2(const double* __restrict__ part, const float* __restrict__ bfc2,
                                                float* __restrict__ out){
  __shared__ double sd[256];
  int tid = threadIdx.x;
  sd[tid] = part[tid]; __syncthreads();
  for (int off = 128; off > 0; off >>= 1){
    if (tid < off) sd[tid] += sd[tid + off];
    __syncthreads();
  }
  if (tid == 0) out[0] = (float)(sd[0] + (double)bfc2[0]);
}

// ---------------- host ----------------
extern "C" void kernel_launch(void* const* d_in, const int* in_sizes, int n_in,
                              void* d_out, int out_size, void* d_ws, size_t ws_size,
                              hipStream_t stream){
  const float* x    = (const float*)d_in[0];
  const int*   ei   = (const int*)d_in[1];
  const float* W0a  = (const float*)d_in[2];
  const float* b0a  = (const float*)d_in[3];
  const float* W0b  = (const float*)d_in[4];
  const float* b0b  = (const float*)d_in[5];
  const float* W1a  = (const float*)d_in[6];
  const float* b1a  = (const float*)d_in[7];
  const float* W1b  = (const float*)d_in[8];
  const float* b1b  = (const float*)d_in[9];
  const float* W2a  = (const float*)d_in[10];
  const float* b2a  = (const float*)d_in[11];
  const float* W2b  = (const float*)d_in[12];
  const float* b2b  = (const float*)d_in[13];
  const float* Wih_f = (const float*)d_in[14];
  const float* Whh_f = (const float*)d_in[15];
  const float* bih_f = (const float*)d_in[16];
  const float* bhh_f = (const float*)d_in[17];
  const float* Wih_b = (const float*)d_in[18];
  const float* Whh_b = (const float*)d_in[19];
  const float* bih_b = (const float*)d_in[20];
  const float* bhh_b = (const float*)d_in[21];
  const float* Watt = (const float*)d_in[22];
  const float* batt = (const float*)d_in[23];
  const float* Wlin = (const float*)d_in[24];
  const float* blin = (const float*)d_in[25];
  const float* Wfc1 = (const float*)d_in[26];
  const float* bfc1 = (const float*)d_in[27];
  const float* Wfc2 = (const float*)d_in[28];
  const float* bfc2 = (const float*)d_in[29];
  float* out = (float*)d_out;

  const int N = in_sizes[0] / 128;
  const int E = in_sizes[1] / 2;
  const int* src = ei;
  const int* dst = ei + E;

  uint8_t* w8 = (uint8_t*)d_ws;
  size_t off = 0;
  auto alloc = [&](size_t bytes) -> void* {
    void* p = w8 + off;
    off = (off + bytes + 255) & ~(size_t)255;
    return p;
  };
  int*    deg    = (int*)   alloc((size_t)N*4);
  int*    fill   = (int*)   alloc((size_t)N*4);
  int*    indptr = (int*)   alloc(((size_t)N+1)*4);
  int*    col    = (int*)   alloc((size_t)E*4);
  int*    bsum   = (int*)   alloc(2048);
  int*    boffs  = (int*)   alloc(2048);
  float*  h1     = (float*) alloc((size_t)N*64*4);
  float*  h2     = (float*) alloc((size_t)N*64*4);
  float*  h3     = (float*) alloc((size_t)N*64*4);
  float*  aF     = (float*) alloc((size_t)3*N*4);
  float*  aB     = (float*) alloc((size_t)3*N*4);
  float*  vbuf   = (float*) alloc((size_t)N*4);
  double* part   = (double*)alloc(256*8);
  u16*    Wpf    = (u16*)   alloc((size_t)10*12*64*8*2);
  u16*    Wpb    = (u16*)   alloc((size_t)10*12*64*8*2);
  float4* Bpf    = (float4*)alloc((size_t)96*16);
  float4* Bpb    = (float4*)alloc((size_t)96*16);
  u16*    Wg0a   = (u16*)   alloc((size_t)128*128*2);
  u16*    Wg0b   = (u16*)   alloc((size_t)64*128*2);
  u16*    Wg1a   = (u16*)   alloc((size_t)64*128*2);
  u16*    Wg1b   = (u16*)   alloc((size_t)64*128*2);
  u16*    Wg2a   = (u16*)   alloc((size_t)64*128*2);
  u16*    Wg2b   = (u16*)   alloc((size_t)64*128*2);
  u16*    WgL    = (u16*)   alloc((size_t)64*128*2);
  float*  P      = (float*) alloc((size_t)N*192*4);
  if (off > ws_size) return;
  float* ybuf = P;
  float* zbuf = P + (size_t)N*64;

  hipMemsetAsync(deg,  0, (size_t)N*4, stream);
  hipMemsetAsync(fill, 0, (size_t)N*4, stream);

  int gE = (E + 255) / 256;
  int nb1 = (N + 255) / 256;
  int gG = (N + 63) / 64;
  int gA = (N + 15) / 16;
  int gL = (N + 31) / 32;

  // weight prepack (independent of CSR)
  k_packW1<<<240, 256, 0, stream>>>(Wih_f, Whh_f, Wpf);
  k_packW1<<<240, 256, 0, stream>>>(Wih_b, Whh_b, Wpb);
  k_packB<<<1, 128, 0, stream>>>(bih_f, bhh_f, Bpf);
  k_packB<<<1, 128, 0, stream>>>(bih_b, bhh_b, Bpb);
  k_packG<<<64, 256, 0, stream>>>(W0a, Wg0a, 128);
  k_packG<<<32, 256, 0, stream>>>(W0b, Wg0b, 64);
  k_packG<<<32, 256, 0, stream>>>(W1a, Wg1a, 64);
  k_packG<<<32, 256, 0, stream>>>(W1b, Wg1b, 64);
  k_packG<<<32, 256, 0, stream>>>(W2a, Wg2a, 64);
  k_packG<<<32, 256, 0, stream>>>(W2b, Wg2b, 64);
  k_packG<<<32, 256, 0, stream>>>(Wlin, WgL, 64);

  k_deg  <<<gE, 256, 0, stream>>>(dst, deg, E);
  k_scan1<<<nb1, 256, 0, stream>>>(deg, indptr, bsum, N);
  k_scan2<<<1, 512, 0, stream>>>(bsum, boffs, indptr, nb1, N);
  k_scan3<<<nb1, 256, 0, stream>>>(indptr, boffs, N);
  k_fill <<<gE, 256, 0, stream>>>(src, dst, indptr, fill, col, E);

  // ---- GIN layer 0 ----
  k_mfgemm<128,0><<<gG, 256, 0, stream>>>(x, Wg0a, nullptr, ybuf, N);
  k_agg<64><<<gA, 256, 0, stream>>>(ybuf, indptr, col, b0a, zbuf, N);
  k_mfgemm2<<<gG, 256, 0, stream>>>(zbuf, Wg0b, b0b, Wg1a, h1, ybuf, N);
  // ---- GIN layer 1 ----
  k_agg<64><<<gA, 256, 0, stream>>>(ybuf, indptr, col, b1a, zbuf, N);
  k_mfgemm2<<<gG, 256, 0, stream>>>(zbuf, Wg1b, b1b, Wg2a, h2, ybuf, N);
  // ---- GIN layer 2 ----
  k_agg<64><<<gA, 256, 0, stream>>>(ybuf, indptr, col, b2a, zbuf, N);
  k_mfgemm<64,1><<<gG, 256, 0, stream>>>(zbuf, Wg2b, b2b, h3, N);

  // ---- LSTM: both directions in one dispatch ----
  k_lstm5<<<2*gL, 256, 0, stream>>>(h1, h2, h3, Wpf, Wpb, Bpf, Bpb, Watt, batt,
                                    aF, aB, gL, N);

  // ---- JK attention + linear + fc1 + leaky (MFMA) ----
  k_jk2<<<gG, 256, 0, stream>>>(aF, aB, h1, h2, h3, WgL, blin, Wfc1, bfc1, vbuf, N);

  // ---- final dot ----
  k_final1<<<256, 256, 0, stream>>>(Wfc2, vbuf, part, N);
  k_final2<<<1, 256, 0, stream>>>(part, bfc2, out);
}

// Round 15
// 626.440 us; speedup vs baseline: 1.3467x; 1.0550x over previous
//
#include <hip/hip_runtime.h>
#include <stdint.h>

typedef unsigned short u16;
typedef unsigned int u32;
using short8 = __attribute__((ext_vector_type(8))) short;
using f32x16 = __attribute__((ext_vector_type(16))) float;

__device__ __forceinline__ float sigf(float x){
  return __builtin_amdgcn_rcpf(1.0f + __expf(-x));
}
__device__ __forceinline__ float tanh_f(float x){
  return 1.0f - 2.0f*__builtin_amdgcn_rcpf(1.0f + __expf(2.0f*x));
}
__device__ __forceinline__ u16 f2bf(float f){
  u32 u = __float_as_uint(f);
  u += 0x7FFFu + ((u>>16)&1u);
  return (u16)(u>>16);
}
__device__ __forceinline__ float bf2f(u16 h){ return __uint_as_float(((u32)h)<<16); }

// ---------------- CSR build ----------------
__global__ void k_deg(const int* __restrict__ dst, int* __restrict__ deg, int E){
  int i = blockIdx.x*256 + threadIdx.x;
  if (i < E) atomicAdd(&deg[dst[i]], 1);
}

__global__ __launch_bounds__(256) void k_scan1(const int* __restrict__ deg, int* __restrict__ indptr,
                                               int* __restrict__ bsum, int N){
  __shared__ int s[256];
  int tid = threadIdx.x;
  int i = blockIdx.x*256 + tid;
  int v = (i < N) ? deg[i] : 0;
  s[tid] = v; __syncthreads();
  for (int off=1; off<256; off<<=1){
    int t = (tid>=off) ? s[tid-off] : 0;
    __syncthreads();
    s[tid] += t;
    __syncthreads();
  }
  if (i < N) indptr[i] = s[tid] - v;
  if (tid == 255) bsum[blockIdx.x] = s[255];
}

__global__ __launch_bounds__(512) void k_scan2(const int* __restrict__ bsum, int* __restrict__ boffs,
                                               int* __restrict__ indptr, int nb, int N){
  __shared__ int s[512];
  int tid = threadIdx.x;
  int v = (tid < nb) ? bsum[tid] : 0;
  s[tid] = v; __syncthreads();
  for (int off=1; off<512; off<<=1){
    int t = (tid>=off) ? s[tid-off] : 0;
    __syncthreads();
    s[tid] += t;
    __syncthreads();
  }
  boffs[tid] = s[tid] - v;
  if (tid == nb-1) indptr[N] = s[tid];
}

__global__ __launch_bounds__(256) void k_scan3(int* __restrict__ indptr, const int* __restrict__ boffs, int N){
  int i = blockIdx.x*256 + threadIdx.x;
  if (i < N) indptr[i] += boffs[blockIdx.x];
}

__global__ void k_fill(const int* __restrict__ src, const int* __restrict__ dst,
                       const int* __restrict__ indptr, int* __restrict__ fill,
                       int* __restrict__ col, int E){
  int i = blockIdx.x*256 + threadIdx.x;
  if (i < E){
    int d = dst[i];
    int r = atomicAdd(&fill[d], 1);
    col[indptr[d] + r] = src[i];
  }
}

// ---------------- aggregation (proven): z[n] = relu( y[n] + sum y[src] + b ) ----------------
template<int F>
__global__ __launch_bounds__(256) void k_agg(const float* __restrict__ y, const int* __restrict__ indptr,
                                             const int* __restrict__ col, const float* __restrict__ bias,
                                             float* __restrict__ z, int N){
  constexpr int TPN = F/4;
  constexpr int NPB = 256/TPN;
  int n = blockIdx.x*NPB + threadIdx.x/TPN;
  int lane = threadIdx.x % TPN;
  if (n >= N) return;
  const float4* hv = (const float4*)y;
  float4 acc = hv[(size_t)n*TPN + lane];
  int s = indptr[n], e = indptr[n+1];
  int p = s;
  for (; p + 8 <= e; p += 8){
    int c8[8];
    #pragma unroll
    for (int i=0;i<8;++i) c8[i] = col[p+i];
    #pragma unroll
    for (int i=0;i<8;++i){
      float4 x = hv[(size_t)c8[i]*TPN + lane];
      acc.x += x.x; acc.y += x.y; acc.z += x.z; acc.w += x.w;
    }
  }
  for (; p < e; ++p){
    float4 x = hv[(size_t)col[p]*TPN + lane];
    acc.x += x.x; acc.y += x.y; acc.z += x.z; acc.w += x.w;
  }
  float4 b4 = ((const float4*)bias)[lane];
  acc.x = fmaxf(acc.x + b4.x, 0.f);
  acc.y = fmaxf(acc.y + b4.y, 0.f);
  acc.z = fmaxf(acc.z + b4.z, 0.f);
  acc.w = fmaxf(acc.w + b4.w, 0.f);
  ((float4*)z)[(size_t)n*TPN + lane] = acc;
}

// ---------------- GIN GEMM weight prepack: frag-linear bf16 hi/lo ----------------
__global__ __launch_bounds__(256) void k_packG(const float* __restrict__ W, u16* __restrict__ Wg, int K){
  int idx = blockIdx.x*256 + threadIdx.x;
  if (idx >= K*128) return;
  int i  = idx & 7;
  int l  = (idx>>3) & 63;
  int p  = (idx>>9) & 1;
  int rt = (idx>>10) & 1;
  int kt = idx >> 11;
  int j  = rt*32 + (l & 31);
  int k  = kt*16 + ((l>>5)<<3) + i;
  float v = W[(size_t)j*K + k];
  u16 h = f2bf(v);
  Wg[idx] = p ? f2bf(v - bf2f(h)) : h;
}

__device__ __forceinline__ void cvt8p(const float (&v)[8], u32 (&hw)[4], u32 (&lw)[4]){
  #pragma unroll
  for (int i=0;i<4;++i){
    u16 h0=f2bf(v[2*i]),   h1=f2bf(v[2*i+1]);
    u16 l0=f2bf(v[2*i]-bf2f(h0)), l1=f2bf(v[2*i+1]-bf2f(h1));
    hw[i]= (u32)h0 | ((u32)h1<<16);
    lw[i]= (u32)l0 | ((u32)l1<<16);
  }
}

// stage 8 f32 values into frag-linear hi/lo planes (node,kc addressing)
__device__ __forceinline__ void stageG(const float (&v)[8], u16* __restrict__ BH, u16* __restrict__ BL,
                                       int node, int kc, int NKT){
  u32 hw[4], lw[4];
  cvt8p(v, hw, lw);
  int kt = kc >> 1, h2 = kc & 1;
  int sl = (((h2<<5) | (node&31)) ^ (kc & 7));
  int addr = (((node>>5)*NKT + kt)<<9) + (sl<<3);
  *(uint4*)(BH + addr) = make_uint4(hw[0],hw[1],hw[2],hw[3]);
  *(uint4*)(BL + addr) = make_uint4(lw[0],lw[1],lw[2],lw[3]);
}

// ---------------- MFMA GEMM (single): out[n][j] = act( A@W^T + b ) ----------------
template<int K, int ACT>
__global__ __launch_bounds__(256,2) void k_mfgemm(const float* __restrict__ A, const u16* __restrict__ Wg,
                                                  const float* __restrict__ bias, float* __restrict__ out,
                                                  int N){
  constexpr int NKT = K/16;
  __shared__ u16 BH[2*NKT*512];
  __shared__ u16 BL[2*NKT*512];
  const int tid = threadIdx.x;
  const int l = tid & 63;
  const int w = __builtin_amdgcn_readfirstlane(tid >> 6);
  const int rt = w >> 1, nt = w & 1;
  const int nb = blockIdx.x * 64;
  const int hi = l >> 5;

  for (int u = tid; u < 64*(K/8); u += 256){
    int node = u / (K/8);
    int kc = u % (K/8);
    int n = nb + node;
    float v[8];
    if (n < N){
      const float4* s4 = (const float4*)(A + (size_t)n*K + kc*8);
      float4 a = s4[0], b = s4[1];
      v[0]=a.x; v[1]=a.y; v[2]=a.z; v[3]=a.w; v[4]=b.x; v[5]=b.y; v[6]=b.z; v[7]=b.w;
    } else {
      #pragma unroll
      for (int i=0;i<8;++i) v[i]=0.f;
    }
    stageG(v, BH, BL, node, kc, NKT);
  }
  __syncthreads();

  f32x16 acc;
  #pragma unroll
  for (int r=0;r<16;++r) acc[r] = 0.f;
  const u16* wbase = Wg + ((size_t)rt<<10) + ((size_t)l<<3);
  #pragma unroll
  for (int kt = 0; kt < NKT; ++kt){
    const u16* wk = wbase + (size_t)kt*2048;
    short8 Ah = *(const short8*)(wk);
    short8 Al = *(const short8*)(wk + 512);
    int sl = l ^ (((kt<<1) + hi) & 7);
    int baddr = ((nt*NKT + kt)<<9) + (sl<<3);
    short8 Bh = *(const short8*)(BH + baddr);
    short8 Bl = *(const short8*)(BL + baddr);
    acc = __builtin_amdgcn_mfma_f32_32x32x16_bf16(Ah, Bh, acc, 0,0,0);
    acc = __builtin_amdgcn_mfma_f32_32x32x16_bf16(Ah, Bl, acc, 0,0,0);
    acc = __builtin_amdgcn_mfma_f32_32x32x16_bf16(Al, Bh, acc, 0,0,0);
  }

  const int col = l & 31;
  const int n = nb + nt*32 + col;
  if (n < N){
    #pragma unroll
    for (int g = 0; g < 4; ++g){
      const int j0 = rt*32 + 8*g + 4*hi;
      float4 b4 = bias ? *(const float4*)(bias + j0) : make_float4(0.f,0.f,0.f,0.f);
      float4 o;
      o.x = acc[4*g+0] + b4.x;
      o.y = acc[4*g+1] + b4.y;
      o.z = acc[4*g+2] + b4.z;
      o.w = acc[4*g+3] + b4.w;
      if (ACT){
        o.x = fmaxf(o.x, 0.f); o.y = fmaxf(o.y, 0.f);
        o.z = fmaxf(o.z, 0.f); o.w = fmaxf(o.w, 0.f);
      }
      *(float4*)(out + (size_t)n*64 + j0) = o;
    }
  }
}

// ---------------- fused pair: H = relu(Z@Wb+bb) (store) ; Y = H@Wa (store) ----------------
__global__ __launch_bounds__(256,2) void k_mfgemm2(const float* __restrict__ Z, const u16* __restrict__ Wgb,
                                                   const float* __restrict__ bb, const u16* __restrict__ Wga,
                                                   float* __restrict__ Hout, float* __restrict__ Yout,
                                                   int N){
  __shared__ u16 BH[4096];
  __shared__ u16 BL[4096];
  __shared__ float hX[64][68];
  const int tid = threadIdx.x;
  const int l = tid & 63;
  const int w = __builtin_amdgcn_readfirstlane(tid >> 6);
  const int rt = w >> 1, nt = w & 1;
  const int nb = blockIdx.x * 64;
  const int hi = l >> 5;
  const int col = l & 31;
  const int n = nb + nt*32 + col;

  // phase 1: stage Z
  for (int u = tid; u < 512; u += 256){
    int node = u >> 3;
    int kc = u & 7;
    int nn = nb + node;
    float v[8];
    if (nn < N){
      const float4* s4 = (const float4*)(Z + (size_t)nn*64 + kc*8);
      float4 a = s4[0], b = s4[1];
      v[0]=a.x; v[1]=a.y; v[2]=a.z; v[3]=a.w; v[4]=b.x; v[5]=b.y; v[6]=b.z; v[7]=b.w;
    } else {
      #pragma unroll
      for (int i=0;i<8;++i) v[i]=0.f;
    }
    stageG(v, BH, BL, node, kc, 4);
  }
  __syncthreads();

  f32x16 acc;
  #pragma unroll
  for (int r=0;r<16;++r) acc[r] = 0.f;
  {
    const u16* wbase = Wgb + ((size_t)rt<<10) + ((size_t)l<<3);
    #pragma unroll
    for (int kt = 0; kt < 4; ++kt){
      const u16* wk = wbase + (size_t)kt*2048;
      short8 Ah = *(const short8*)(wk);
      short8 Al = *(const short8*)(wk + 512);
      int sl = l ^ (((kt<<1) + hi) & 7);
      int baddr = ((nt*4 + kt)<<9) + (sl<<3);
      short8 Bh = *(const short8*)(BH + baddr);
      short8 Bl = *(const short8*)(BL + baddr);
      acc = __builtin_amdgcn_mfma_f32_32x32x16_bf16(Ah, Bh, acc, 0,0,0);
      acc = __builtin_amdgcn_mfma_f32_32x32x16_bf16(Ah, Bl, acc, 0,0,0);
      acc = __builtin_amdgcn_mfma_f32_32x32x16_bf16(Al, Bh, acc, 0,0,0);
    }
  }
  {
    const int node = nt*32 + col;
    #pragma unroll
    for (int g = 0; g < 4; ++g){
      const int j0 = rt*32 + 8*g + 4*hi;
      float4 b4 = *(const float4*)(bb + j0);
      float4 o;
      o.x = fmaxf(acc[4*g+0] + b4.x, 0.f);
      o.y = fmaxf(acc[4*g+1] + b4.y, 0.f);
      o.z = fmaxf(acc[4*g+2] + b4.z, 0.f);
      o.w = fmaxf(acc[4*g+3] + b4.w, 0.f);
      if (n < N) *(float4*)(Hout + (size_t)n*64 + j0) = o;
      *(float4*)(&hX[node][j0]) = o;
    }
  }
  __syncthreads();

  // phase 2: restage H from hX
  for (int u = tid; u < 512; u += 256){
    int node = u >> 3;
    int kc = u & 7;
    float v[8];
    #pragma unroll
    for (int i=0;i<8;++i) v[i] = hX[node][kc*8 + i];
    stageG(v, BH, BL, node, kc, 4);
  }
  __syncthreads();

  #pragma unroll
  for (int r=0;r<16;++r) acc[r] = 0.f;
  {
    const u16* wbase = Wga + ((size_t)rt<<10) + ((size_t)l<<3);
    #pragma unroll
    for (int kt = 0; kt < 4; ++kt){
      const u16* wk = wbase + (size_t)kt*2048;
      short8 Ah = *(const short8*)(wk);
      short8 Al = *(const short8*)(wk + 512);
      int sl = l ^ (((kt<<1) + hi) & 7);
      int baddr = ((nt*4 + kt)<<9) + (sl<<3);
      short8 Bh = *(const short8*)(BH + baddr);
      short8 Bl = *(const short8*)(BL + baddr);
      acc = __builtin_amdgcn_mfma_f32_32x32x16_bf16(Ah, Bh, acc, 0,0,0);
      acc = __builtin_amdgcn_mfma_f32_32x32x16_bf16(Ah, Bl, acc, 0,0,0);
      acc = __builtin_amdgcn_mfma_f32_32x32x16_bf16(Al, Bh, acc, 0,0,0);
    }
  }
  if (n < N){
    #pragma unroll
    for (int g = 0; g < 4; ++g){
      const int j0 = rt*32 + 8*g + 4*hi;
      float4 o;
      o.x = acc[4*g+0]; o.y = acc[4*g+1]; o.z = acc[4*g+2]; o.w = acc[4*g+3];
      *(float4*)(Yout + (size_t)n*64 + j0) = o;
    }
  }
}

// ---------------- LSTM weight prepack: fragment-linear bf16, SINGLE plane ----------------
__global__ __launch_bounds__(256) void k_packW1(const float* __restrict__ Wih, const float* __restrict__ Whh,
                                                u16* __restrict__ Wp){
  int idx = blockIdx.x*256 + threadIdx.x;
  if (idx >= 10*12*64*8) return;
  int i  = idx & 7;
  int l  = (idx>>3) & 63;
  int rt = (idx>>9) % 12;
  int kt = (idx>>9) / 12;
  int r  = rt*32 + (l & 31);
  int j  = r >> 2, g = r & 3;
  int row = g*96 + j;
  int k  = kt*16 + ((l>>5)<<3) + i;
  float v = (k < 64) ? Wih[row*64 + k] : Whh[row*96 + (k-64)];
  Wp[idx] = f2bf(v);
}

__global__ __launch_bounds__(128) void k_packB(const float* __restrict__ bih, const float* __restrict__ bhh,
                                               float4* __restrict__ Bp){
  int j = blockIdx.x*128 + threadIdx.x;
  if (j >= 96) return;
  Bp[j] = make_float4(bih[j]+bhh[j], bih[96+j]+bhh[96+j],
                      bih[192+j]+bhh[192+j], bih[288+j]+bhh[288+j]);
}

// ---------------- MFMA LSTM v5c: h kept bf16-only (no lo plane), 22KB LDS ----------------
// X: XH [kt(0..9)][slot(64)][8] u16 (x hi for kt<4, h bf16 for kt>=4);
//    XL [kt(0..3)] only (x lo residual). hFH u16[96][32] h exchange; restage = pure copy.
// Steps 2-3: kt<4 -> 6 MFMAs (x hi/lo), kt>=4 -> 3 MFMAs (h bf16 only).
__device__ __forceinline__ void ldx_regs(const float* __restrict__ seq, int blk, int N, int tid,
                                         float (&v)[8]){
  int node = tid >> 3;
  int kc = tid & 7;
  int n = blk*32 + node;
  if (n < N){
    const float4* s4 = (const float4*)(seq + (size_t)n*64 + kc*8);
    float4 a = s4[0], b = s4[1];
    v[0]=a.x; v[1]=a.y; v[2]=a.z; v[3]=a.w; v[4]=b.x; v[5]=b.y; v[6]=b.z; v[7]=b.w;
  } else {
    #pragma unroll
    for (int i=0;i<8;++i) v[i]=0.f;
  }
}

__device__ __forceinline__ void stage_from_regs(const float (&v)[8], u16* __restrict__ XH,
                                                u16* __restrict__ XL, int tid){
  int node = tid >> 3;
  int kc = tid & 7;
  u32 hw[4], lw[4];
  cvt8p(v, hw, lw);
  int kt = kc >> 1, hi = kc & 1;
  int sl = (((hi<<5) | node) ^ (kc & 7));
  int addr = (kt<<9) + (sl<<3);
  *(uint4*)(XH + addr) = make_uint4(hw[0],hw[1],hw[2],hw[3]);
  *(uint4*)(XL + addr) = make_uint4(lw[0],lw[1],lw[2],lw[3]);
}

__device__ __forceinline__ void restage_h16(const u16 (*hFH)[32], u16* __restrict__ XH, int tid){
  int node = tid & 31;
  #pragma unroll
  for (int q = 0; q < 2; ++q){
    int cc = (tid >> 5) + q*8;
    if (cc < 12){
      int kth = cc >> 1, hi = cc & 1;
      int ktG = kth + 4;
      u32 hw[4];
      #pragma unroll
      for (int i=0;i<4;++i){
        u16 a = hFH[cc*8 + 2*i][node];
        u16 b = hFH[cc*8 + 2*i + 1][node];
        hw[i] = (u32)a | ((u32)b<<16);
      }
      int sl = (((hi<<5) | node) ^ ((2*ktG + hi) & 7));
      int addr = (ktG<<9) + (sl<<3);
      *(uint4*)(XH + addr) = make_uint4(hw[0],hw[1],hw[2],hw[3]);
    }
  }
}

template<int FIRST, int WRITEH>
__device__ __forceinline__ float lstm_step5(const u16* __restrict__ Wp,
    const float4* __restrict__ Bp, const float* __restrict__ WattW,
    const u16* __restrict__ XH, const u16* __restrict__ XL, u16 (*hFH)[32],
    float (&c)[12], int rtg, int l)
{
  constexpr int NKT = FIRST ? 4 : 10;
  const int hi = l >> 5;
  const int col = l & 31;
  f32x16 acc[3];
  #pragma unroll
  for (int t=0;t<3;++t)
    #pragma unroll
    for (int r=0;r<16;++r) acc[t][r] = 0.f;

  const u16* wbase = Wp + (size_t)(rtg*3)*512 + ((size_t)l<<3);
  #pragma unroll
  for (int kt = 0; kt < NKT; ++kt){
    const u16* wk = wbase + (size_t)kt*6144;
    short8 A0 = *(const short8*)(wk);
    short8 A1 = *(const short8*)(wk + 512);
    short8 A2 = *(const short8*)(wk + 1024);
    int sl = l ^ (((kt<<1) + hi) & 7);
    int baddr = (kt<<9) + (sl<<3);
    short8 Bh = *(const short8*)(XH + baddr);
    __builtin_amdgcn_s_setprio(1);
    acc[0] = __builtin_amdgcn_mfma_f32_32x32x16_bf16(A0, Bh, acc[0], 0,0,0);
    acc[1] = __builtin_amdgcn_mfma_f32_32x32x16_bf16(A1, Bh, acc[1], 0,0,0);
    acc[2] = __builtin_amdgcn_mfma_f32_32x32x16_bf16(A2, Bh, acc[2], 0,0,0);
    if (kt < 4){
      short8 Bl = *(const short8*)(XL + baddr);
      acc[0] = __builtin_amdgcn_mfma_f32_32x32x16_bf16(A0, Bl, acc[0], 0,0,0);
      acc[1] = __builtin_amdgcn_mfma_f32_32x32x16_bf16(A1, Bl, acc[1], 0,0,0);
      acc[2] = __builtin_amdgcn_mfma_f32_32x32x16_bf16(A2, Bl, acc[2], 0,0,0);
    }
    __builtin_amdgcn_s_setprio(0);
  }

  float aP = 0.f;
  #pragma unroll
  for (int ti=0;ti<3;++ti){
    #pragma unroll
    for (int rg=0; rg<4; ++rg){
      const int j = (rtg*3+ti)*8 + 2*rg + hi;
      float4 bv = Bp[j];
      float gi = acc[ti][rg*4+0] + bv.x;
      float gf = acc[ti][rg*4+1] + bv.y;
      float gg = acc[ti][rg*4+2] + bv.z;
      float go = acc[ti][rg*4+3] + bv.w;
      const int ci = ti*4 + rg;
      float cp = FIRST ? 0.f : c[ci];
      float cn = sigf(gf)*cp + sigf(gi)*tanh_f(gg);
      float hh = sigf(go)*tanh_f(cn);
      c[ci] = cn;
      aP = fmaf(hh, WattW[j], aP);
      if (WRITEH) hFH[j][col] = f2bf(hh);
    }
  }
  return aP;
}

__global__ __launch_bounds__(256,2) void k_lstm5(
    const float* __restrict__ h1, const float* __restrict__ h2, const float* __restrict__ h3,
    const u16* __restrict__ Wpf, const u16* __restrict__ Wpb,
    const float4* __restrict__ Bpf, const float4* __restrict__ Bpb,
    const float* __restrict__ Watt, const float* __restrict__ batt,
    float* __restrict__ aF, float* __restrict__ aB, int gL, int N)
{
  __shared__ u16 XH[5120];
  __shared__ u16 XL[2048];
  __shared__ u16 hFH[96][32];
  __shared__ float sAl[4][3][32];
  const int tid = threadIdx.x;
  const int l = tid & 63;
  const int rtg = __builtin_amdgcn_readfirstlane(tid >> 6);
  const int dir = (blockIdx.x >= gL) ? 1 : 0;
  const int blk = blockIdx.x - dir*gL;
  const float* sA = dir ? h3 : h1;
  const float* sC = dir ? h1 : h3;
  const u16* Wp = dir ? Wpb : Wpf;
  const float4* Bp = dir ? Bpb : Bpf;
  const float* WattW = Watt + dir*96;
  float* aD = dir ? aB : aF;
  float c[12];
  float a0, a1, a2;
  float xv[8];

  ldx_regs(sA, blk, N, tid, xv);
  stage_from_regs(xv, XH, XL, tid);
  ldx_regs(h2, blk, N, tid, xv);
  __syncthreads();

  a0 = lstm_step5<1,1>(Wp, Bp, WattW, XH, XL, hFH, c, rtg, l);
  __syncthreads();
  stage_from_regs(xv, XH, XL, tid);
  restage_h16(hFH, XH, tid);
  ldx_regs(sC, blk, N, tid, xv);
  __syncthreads();

  a1 = lstm_step5<0,1>(Wp, Bp, WattW, XH, XL, hFH, c, rtg, l);
  __syncthreads();
  stage_from_regs(xv, XH, XL, tid);
  restage_h16(hFH, XH, tid);
  __syncthreads();

  a2 = lstm_step5<0,0>(Wp, Bp, WattW, XH, XL, hFH, c, rtg, l);

  a0 += __shfl_xor(a0, 32);
  a1 += __shfl_xor(a1, 32);
  a2 += __shfl_xor(a2, 32);
  if (l < 32){
    sAl[rtg][0][l] = a0;
    sAl[rtg][1][l] = a1;
    sAl[rtg][2][l] = a2;
  }
  __syncthreads();
  if (tid < 96){
    int s = tid >> 5;
    int node = tid & 31;
    int n = blk*32 + node;
    if (n < N){
      float sum = sAl[0][s][node] + sAl[1][s][node]
                + sAl[2][s][node] + sAl[3][s][node];
      int slice = dir ? (2 - s) : s;
      float v = dir ? sum : (batt[0] + sum);
      aD[(size_t)slice*N + n] = v;
    }
  }
}

// ---------------- JK via MFMA: softmax + xjk + Wlin + fc1-dot + leaky ----------------
__global__ __launch_bounds__(256,2) void k_jk2(const float* __restrict__ aF, const float* __restrict__ aB,
                                               const float* __restrict__ h1, const float* __restrict__ h2,
                                               const float* __restrict__ h3,
                                               const u16* __restrict__ WgL, const float* __restrict__ blin,
                                               const float* __restrict__ Wfc1, const float* __restrict__ bfc1,
                                               float* __restrict__ vout, int N){
  __shared__ u16 BH[4096];
  __shared__ u16 BL[4096];
  __shared__ float sP[4][32];
  const int tid = threadIdx.x;
  const int l = tid & 63;
  const int w = __builtin_amdgcn_readfirstlane(tid >> 6);
  const int rt = w >> 1, nt = w & 1;
  const int nb = blockIdx.x * 64;
  const int hi = l >> 5;
  const int col = l & 31;

  for (int u = tid; u < 512; u += 256){
    int node = u >> 3;
    int kc = u & 7;
    int n = nb + node;
    float v[8];
    if (n < N){
      float a0 = aF[n] + aB[n];
      float a1 = aF[(size_t)N + n] + aB[(size_t)N + n];
      float a2 = aF[(size_t)2*N + n] + aB[(size_t)2*N + n];
      float m = fmaxf(a0, fmaxf(a1, a2));
      float e0 = __expf(a0-m), e1 = __expf(a1-m), e2 = __expf(a2-m);
      float inv = __builtin_amdgcn_rcpf(e0+e1+e2);
      float w0 = e0*inv, w1 = e1*inv, w2 = e2*inv;
      const float4* p1 = (const float4*)(h1 + (size_t)n*64 + kc*8);
      const float4* p2 = (const float4*)(h2 + (size_t)n*64 + kc*8);
      const float4* p3 = (const float4*)(h3 + (size_t)n*64 + kc*8);
      #pragma unroll
      for (int q=0;q<2;++q){
        float4 x1 = p1[q], x2 = p2[q], x3 = p3[q];
        v[4*q+0] = w0*x1.x + w1*x2.x + w2*x3.x;
        v[4*q+1] = w0*x1.y + w1*x2.y + w2*x3.y;
        v[4*q+2] = w0*x1.z + w1*x2.z + w2*x3.z;
        v[4*q+3] = w0*x1.w + w1*x2.w + w2*x3.w;
      }
    } else {
      #pragma unroll
      for (int i=0;i<8;++i) v[i]=0.f;
    }
    stageG(v, BH, BL, node, kc, 4);
  }
  __syncthreads();

  f32x16 acc;
  #pragma unroll
  for (int r=0;r<16;++r) acc[r] = 0.f;
  const u16* wbase = WgL + ((size_t)rt<<10) + ((size_t)l<<3);
  #pragma unroll
  for (int kt = 0; kt < 4; ++kt){
    const u16* wk = wbase + (size_t)kt*2048;
    short8 Ah = *(const short8*)(wk);
    short8 Al = *(const short8*)(wk + 512);
    int sl = l ^ (((kt<<1) + hi) & 7);
    int baddr = ((nt*4 + kt)<<9) + (sl<<3);
    short8 Bh = *(const short8*)(BH + baddr);
    short8 Bl = *(const short8*)(BL + baddr);
    acc = __builtin_amdgcn_mfma_f32_32x32x16_bf16(Ah, Bh, acc, 0,0,0);
    acc = __builtin_amdgcn_mfma_f32_32x32x16_bf16(Ah, Bl, acc, 0,0,0);
    acc = __builtin_amdgcn_mfma_f32_32x32x16_bf16(Al, Bh, acc, 0,0,0);
  }

  float p = 0.f;
  #pragma unroll
  for (int g = 0; g < 4; ++g){
    #pragma unroll
    for (int rg = 0; rg < 4; ++rg){
      const int j = rt*32 + 8*g + 4*hi + rg;
      p += (acc[4*g+rg] + blin[j]) * Wfc1[j];
    }
  }
  p += __shfl_xor(p, 32);
  if (l < 32) sP[w][l] = p;
  __syncthreads();
  if (tid < 64){
    int node = tid;
    int nt2 = node >> 5, c2 = node & 31;
    int n = nb + node;
    if (n < N){
      float t = sP[nt2][c2] + sP[2+nt2][c2] + bfc1[0];
      vout[n] = t >= 0.f ? t : 0.01f*t;
    }
  }
}

// ---------------- final dot (deterministic two-stage, f64 accum) ----------------
__global__ __launch_bounds__(256) void k_final1(const float* __restrict__ w, const float* __restrict__ v,
                                                double* __restrict__ part, int N){
  __shared__ double sd[256];
  int tid = threadIdx.x;
  double a = 0.0;
  for (int i = blockIdx.x*256 + tid; i < N; i += 256*256)
    a += (double)(w[i] * v[i]);
  sd[tid] = a; __syncthreads();
  for (int off = 128; off > 0; off >>= 1){
    if (tid < off) sd[tid] += sd[tid + off];
    __syncthreads();
  }
  if (tid == 0) part[blockIdx.x] = sd[0];
}

__global__ __launch_bounds__(256) void k_final2(const double* __restrict__ part, const float* __restrict__ bfc2,
                                                float* __restrict__ out){
  __shared__ double sd[256];
  int tid = threadIdx.x;
  sd[tid] = part[tid]; __syncthreads();
  for (int off = 128; off > 0; off >>= 1){
    if (tid < off) sd[tid] += sd[tid + off];
    __syncthreads();
  }
  if (tid == 0) out[0] = (float)(sd[0] + (double)bfc2[0]);
}

// ---------------- host ----------------
extern "C" void kernel_launch(void* const* d_in, const int* in_sizes, int n_in,
                              void* d_out, int out_size, void* d_ws, size_t ws_size,
                              hipStream_t stream){
  const float* x    = (const float*)d_in[0];
  const int*   ei   = (const int*)d_in[1];
  const float* W0a  = (const float*)d_in[2];
  const float* b0a  = (const float*)d_in[3];
  const float* W0b  = (const float*)d_in[4];
  const float* b0b  = (const float*)d_in[5];
  const float* W1a  = (const float*)d_in[6];
  const float* b1a  = (const float*)d_in[7];
  const float* W1b  = (const float*)d_in[8];
  const float* b1b  = (const float*)d_in[9];
  const float* W2a  = (const float*)d_in[10];
  const float* b2a  = (const float*)d_in[11];
  const float* W2b  = (const float*)d_in[12];
  const float* b2b  = (const float*)d_in[13];
  const float* Wih_f = (const float*)d_in[14];
  const float* Whh_f = (const float*)d_in[15];
  const float* bih_f = (const float*)d_in[16];
  const float* bhh_f = (const float*)d_in[17];
  const float* Wih_b = (const float*)d_in[18];
  const float* Whh_b = (const float*)d_in[19];
  const float* bih_b = (const float*)d_in[20];
  const float* bhh_b = (const float*)d_in[21];
  const float* Watt = (const float*)d_in[22];
  const float* batt = (const float*)d_in[23];
  const float* Wlin = (const float*)d_in[24];
  const float* blin = (const float*)d_in[25];
  const float* Wfc1 = (const float*)d_in[26];
  const float* bfc1 = (const float*)d_in[27];
  const float* Wfc2 = (const float*)d_in[28];
  const float* bfc2 = (const float*)d_in[29];
  float* out = (float*)d_out;

  const int N = in_sizes[0] / 128;
  const int E = in_sizes[1] / 2;
  const int* src = ei;
  const int* dst = ei + E;

  uint8_t* w8 = (uint8_t*)d_ws;
  size_t off = 0;
  auto alloc = [&](size_t bytes) -> void* {
    void* p = w8 + off;
    off = (off + bytes + 255) & ~(size_t)255;
    return p;
  };
  int*    deg    = (int*)   alloc((size_t)N*4);
  int*    fill   = (int*)   alloc((size_t)N*4);
  int*    indptr = (int*)   alloc(((size_t)N+1)*4);
  int*    col    = (int*)   alloc((size_t)E*4);
  int*    bsum   = (int*)   alloc(2048);
  int*    boffs  = (int*)   alloc(2048);
  float*  h1     = (float*) alloc((size_t)N*64*4);
  float*  h2     = (float*) alloc((size_t)N*64*4);
  float*  h3     = (float*) alloc((size_t)N*64*4);
  float*  aF     = (float*) alloc((size_t)3*N*4);
  float*  aB     = (float*) alloc((size_t)3*N*4);
  float*  vbuf   = (float*) alloc((size_t)N*4);
  double* part   = (double*)alloc(256*8);
  u16*    Wpf    = (u16*)   alloc((size_t)10*12*64*8*2);
  u16*    Wpb    = (u16*)   alloc((size_t)10*12*64*8*2);
  float4* Bpf    = (float4*)alloc((size_t)96*16);
  float4* Bpb    = (float4*)alloc((size_t)96*16);
  u16*    Wg0a   = (u16*)   alloc((size_t)128*128*2);
  u16*    Wg0b   = (u16*)   alloc((size_t)64*128*2);
  u16*    Wg1a   = (u16*)   alloc((size_t)64*128*2);
  u16*    Wg1b   = (u16*)   alloc((size_t)64*128*2);
  u16*    Wg2a   = (u16*)   alloc((size_t)64*128*2);
  u16*    Wg2b   = (u16*)   alloc((size_t)64*128*2);
  u16*    WgL    = (u16*)   alloc((size_t)64*128*2);
  float*  P      = (float*) alloc((size_t)N*192*4);
  if (off > ws_size) return;
  float* ybuf = P;
  float* zbuf = P + (size_t)N*64;

  hipMemsetAsync(deg,  0, (size_t)N*4, stream);
  hipMemsetAsync(fill, 0, (size_t)N*4, stream);

  int gE = (E + 255) / 256;
  int nb1 = (N + 255) / 256;
  int gG = (N + 63) / 64;
  int gA = (N + 15) / 16;
  int gL = (N + 31) / 32;

  // weight prepack (independent of CSR)
  k_packW1<<<240, 256, 0, stream>>>(Wih_f, Whh_f, Wpf);
  k_packW1<<<240, 256, 0, stream>>>(Wih_b, Whh_b, Wpb);
  k_packB<<<1, 128, 0, stream>>>(bih_f, bhh_f, Bpf);
  k_packB<<<1, 128, 0, stream>>>(bih_b, bhh_b, Bpb);
  k_packG<<<64, 256, 0, stream>>>(W0a, Wg0a, 128);
  k_packG<<<32, 256, 0, stream>>>(W0b, Wg0b, 64);
  k_packG<<<32, 256, 0, stream>>>(W1a, Wg1a, 64);
  k_packG<<<32, 256, 0, stream>>>(W1b, Wg1b, 64);
  k_packG<<<32, 256, 0, stream>>>(W2a, Wg2a, 64);
  k_packG<<<32, 256, 0, stream>>>(W2b, Wg2b, 64);
  k_packG<<<32, 256, 0, stream>>>(Wlin, WgL, 64);

  k_deg  <<<gE, 256, 0, stream>>>(dst, deg, E);
  k_scan1<<<nb1, 256, 0, stream>>>(deg, indptr, bsum, N);
  k_scan2<<<1, 512, 0, stream>>>(bsum, boffs, indptr, nb1, N);
  k_scan3<<<nb1, 256, 0, stream>>>(indptr, boffs, N);
  k_fill <<<gE, 256, 0, stream>>>(src, dst, indptr, fill, col, E);

  // ---- GIN layer 0 ----
  k_mfgemm<128,0><<<gG, 256, 0, stream>>>(x, Wg0a, nullptr, ybuf, N);
  k_agg<64><<<gA, 256, 0, stream>>>(ybuf, indptr, col, b0a, zbuf, N);
  k_mfgemm2<<<gG, 256, 0, stream>>>(zbuf, Wg0b, b0b, Wg1a, h1, ybuf, N);
  // ---- GIN layer 1 ----
  k_agg<64><<<gA, 256, 0, stream>>>(ybuf, indptr, col, b1a, zbuf, N);
  k_mfgemm2<<<gG, 256, 0, stream>>>(zbuf, Wg1b, b1b, Wg2a, h2, ybuf, N);
  // ---- GIN layer 2 ----
  k_agg<64><<<gA, 256, 0, stream>>>(ybuf, indptr, col, b2a, zbuf, N);
  k_mfgemm<64,1><<<gG, 256, 0, stream>>>(zbuf, Wg2b, b2b, h3, N);

  // ---- LSTM: both directions in one dispatch ----
  k_lstm5<<<2*gL, 256, 0, stream>>>(h1, h2, h3, Wpf, Wpb, Bpf, Bpb, Watt, batt,
                                    aF, aB, gL, N);

  // ---- JK attention + linear + fc1 + leaky (MFMA) ----
  k_jk2<<<gG, 256, 0, stream>>>(aF, aB, h1, h2, h3, WgL, blin, Wfc1, bfc1, vbuf, N);

  // ---- final dot ----
  k_final1<<<256, 256, 0, stream>>>(Wfc2, vbuf, part, N);
  k_final2<<<1, 256, 0, stream>>>(part, bfc2, out);
}

// Round 16
// 591.997 us; speedup vs baseline: 1.4250x; 1.0582x over previous
//
#include <hip/hip_runtime.h>
#include <stdint.h>

typedef unsigned short u16;
typedef unsigned int u32;
using short8 = __attribute__((ext_vector_type(8))) short;
using f32x16 = __attribute__((ext_vector_type(16))) float;

__device__ __forceinline__ float sigf(float x){
  return __builtin_amdgcn_rcpf(1.0f + __expf(-x));
}
__device__ __forceinline__ float tanh_f(float x){
  return 1.0f - 2.0f*__builtin_amdgcn_rcpf(1.0f + __expf(2.0f*x));
}
__device__ __forceinline__ u16 f2bf(float f){
  u32 u = __float_as_uint(f);
  u += 0x7FFFu + ((u>>16)&1u);
  return (u16)(u>>16);
}
__device__ __forceinline__ float bf2f(u16 h){ return __uint_as_float(((u32)h)<<16); }

// ---------------- CSR build ----------------
__global__ void k_deg(const int* __restrict__ dst, int* __restrict__ deg, int E){
  int i = blockIdx.x*256 + threadIdx.x;
  if (i < E) atomicAdd(&deg[dst[i]], 1);
}

__global__ __launch_bounds__(256) void k_scan1(const int* __restrict__ deg, int* __restrict__ indptr,
                                               int* __restrict__ bsum, int N){
  __shared__ int s[256];
  int tid = threadIdx.x;
  int i = blockIdx.x*256 + tid;
  int v = (i < N) ? deg[i] : 0;
  s[tid] = v; __syncthreads();
  for (int off=1; off<256; off<<=1){
    int t = (tid>=off) ? s[tid-off] : 0;
    __syncthreads();
    s[tid] += t;
    __syncthreads();
  }
  if (i < N) indptr[i] = s[tid] - v;
  if (tid == 255) bsum[blockIdx.x] = s[255];
}

__global__ __launch_bounds__(512) void k_scan2(const int* __restrict__ bsum, int* __restrict__ boffs,
                                               int* __restrict__ indptr, int nb, int N){
  __shared__ int s[512];
  int tid = threadIdx.x;
  int v = (tid < nb) ? bsum[tid] : 0;
  s[tid] = v; __syncthreads();
  for (int off=1; off<512; off<<=1){
    int t = (tid>=off) ? s[tid-off] : 0;
    __syncthreads();
    s[tid] += t;
    __syncthreads();
  }
  boffs[tid] = s[tid] - v;
  if (tid == nb-1) indptr[N] = s[tid];
}

__global__ __launch_bounds__(256) void k_scan3(int* __restrict__ indptr, const int* __restrict__ boffs, int N){
  int i = blockIdx.x*256 + threadIdx.x;
  if (i < N) indptr[i] += boffs[blockIdx.x];
}

__global__ void k_fill(const int* __restrict__ src, const int* __restrict__ dst,
                       const int* __restrict__ indptr, int* __restrict__ fill,
                       int* __restrict__ col, int E){
  int i = blockIdx.x*256 + threadIdx.x;
  if (i < E){
    int d = dst[i];
    int r = atomicAdd(&fill[d], 1);
    col[indptr[d] + r] = src[i];
  }
}

// ---------------- aggregation (proven): z[n] = relu( y[n] + sum y[src] + b ) ----------------
template<int F>
__global__ __launch_bounds__(256) void k_agg(const float* __restrict__ y, const int* __restrict__ indptr,
                                             const int* __restrict__ col, const float* __restrict__ bias,
                                             float* __restrict__ z, int N){
  constexpr int TPN = F/4;
  constexpr int NPB = 256/TPN;
  int n = blockIdx.x*NPB + threadIdx.x/TPN;
  int lane = threadIdx.x % TPN;
  if (n >= N) return;
  const float4* hv = (const float4*)y;
  float4 acc = hv[(size_t)n*TPN + lane];
  int s = indptr[n], e = indptr[n+1];
  int p = s;
  for (; p + 8 <= e; p += 8){
    int c8[8];
    #pragma unroll
    for (int i=0;i<8;++i) c8[i] = col[p+i];
    #pragma unroll
    for (int i=0;i<8;++i){
      float4 x = hv[(size_t)c8[i]*TPN + lane];
      acc.x += x.x; acc.y += x.y; acc.z += x.z; acc.w += x.w;
    }
  }
  for (; p < e; ++p){
    float4 x = hv[(size_t)col[p]*TPN + lane];
    acc.x += x.x; acc.y += x.y; acc.z += x.z; acc.w += x.w;
  }
  float4 b4 = ((const float4*)bias)[lane];
  acc.x = fmaxf(acc.x + b4.x, 0.f);
  acc.y = fmaxf(acc.y + b4.y, 0.f);
  acc.z = fmaxf(acc.z + b4.z, 0.f);
  acc.w = fmaxf(acc.w + b4.w, 0.f);
  ((float4*)z)[(size_t)n*TPN + lane] = acc;
}

// ---------------- pack bodies ----------------
__device__ __forceinline__ void packW1_body(int idx, const float* __restrict__ Wih,
                                            const float* __restrict__ Whh, u16* __restrict__ Wp){
  if (idx >= 10*12*64*8) return;
  int i  = idx & 7;
  int l  = (idx>>3) & 63;
  int rt = (idx>>9) % 12;
  int kt = (idx>>9) / 12;
  int r  = rt*32 + (l & 31);
  int j  = r >> 2, g = r & 3;
  int row = g*96 + j;
  int k  = kt*16 + ((l>>5)<<3) + i;
  float v = (k < 64) ? Wih[row*64 + k] : Whh[row*96 + (k-64)];
  Wp[idx] = f2bf(v);
}

__device__ __forceinline__ void packG_body(int idx, const float* __restrict__ W,
                                           u16* __restrict__ Wg, int K){
  if (idx >= K*128) return;
  int i  = idx & 7;
  int l  = (idx>>3) & 63;
  int p  = (idx>>9) & 1;
  int rt = (idx>>10) & 1;
  int kt = idx >> 11;
  int j  = rt*32 + (l & 31);
  int k  = kt*16 + ((l>>5)<<3) + i;
  float v = W[(size_t)j*K + k];
  u16 h = f2bf(v);
  Wg[idx] = p ? f2bf(v - bf2f(h)) : h;
}

// one dispatch for every weight prepack
__global__ __launch_bounds__(256) void k_packAll(
    const float* __restrict__ Wih_f, const float* __restrict__ Whh_f,
    const float* __restrict__ Wih_b, const float* __restrict__ Whh_b,
    const float* __restrict__ bih_f, const float* __restrict__ bhh_f,
    const float* __restrict__ bih_b, const float* __restrict__ bhh_b,
    const float* __restrict__ W0a, const float* __restrict__ W0b,
    const float* __restrict__ W1a, const float* __restrict__ W1b,
    const float* __restrict__ W2a, const float* __restrict__ W2b,
    const float* __restrict__ Wlin,
    u16* __restrict__ Wpf, u16* __restrict__ Wpb,
    float4* __restrict__ Bpf, float4* __restrict__ Bpb,
    u16* __restrict__ Wg0a, u16* __restrict__ Wg0b,
    u16* __restrict__ Wg1a, u16* __restrict__ Wg1b,
    u16* __restrict__ Wg2a, u16* __restrict__ Wg2b,
    u16* __restrict__ WgL)
{
  int b = blockIdx.x;
  int tid = threadIdx.x;
  if (b < 240){ packW1_body(b*256+tid, Wih_f, Whh_f, Wpf); return; }
  b -= 240;
  if (b < 240){ packW1_body(b*256+tid, Wih_b, Whh_b, Wpb); return; }
  b -= 240;
  if (b == 0){
    if (tid < 96){
      int j = tid;
      Bpf[j] = make_float4(bih_f[j]+bhh_f[j], bih_f[96+j]+bhh_f[96+j],
                           bih_f[192+j]+bhh_f[192+j], bih_f[288+j]+bhh_f[288+j]);
    } else if (tid >= 128 && tid < 224){
      int j = tid - 128;
      Bpb[j] = make_float4(bih_b[j]+bhh_b[j], bih_b[96+j]+bhh_b[96+j],
                           bih_b[192+j]+bhh_b[192+j], bih_b[288+j]+bhh_b[288+j]);
    }
    return;
  }
  b -= 1;
  if (b < 64){ packG_body(b*256+tid, W0a, Wg0a, 128); return; }
  b -= 64;
  if (b < 32){ packG_body(b*256+tid, W0b, Wg0b, 64); return; }
  b -= 32;
  if (b < 32){ packG_body(b*256+tid, W1a, Wg1a, 64); return; }
  b -= 32;
  if (b < 32){ packG_body(b*256+tid, W1b, Wg1b, 64); return; }
  b -= 32;
  if (b < 32){ packG_body(b*256+tid, W2a, Wg2a, 64); return; }
  b -= 32;
  if (b < 32){ packG_body(b*256+tid, W2b, Wg2b, 64); return; }
  b -= 32;
  packG_body(b*256+tid, Wlin, WgL, 64);
}

__device__ __forceinline__ void cvt8p(const float (&v)[8], u32 (&hw)[4], u32 (&lw)[4]){
  #pragma unroll
  for (int i=0;i<4;++i){
    u16 h0=f2bf(v[2*i]),   h1=f2bf(v[2*i+1]);
    u16 l0=f2bf(v[2*i]-bf2f(h0)), l1=f2bf(v[2*i+1]-bf2f(h1));
    hw[i]= (u32)h0 | ((u32)h1<<16);
    lw[i]= (u32)l0 | ((u32)l1<<16);
  }
}

// stage 8 f32 values into frag-linear hi/lo planes (node,kc addressing)
__device__ __forceinline__ void stageG(const float (&v)[8], u16* __restrict__ BH, u16* __restrict__ BL,
                                       int node, int kc, int NKT){
  u32 hw[4], lw[4];
  cvt8p(v, hw, lw);
  int kt = kc >> 1, h2 = kc & 1;
  int sl = (((h2<<5) | (node&31)) ^ (kc & 7));
  int addr = (((node>>5)*NKT + kt)<<9) + (sl<<3);
  *(uint4*)(BH + addr) = make_uint4(hw[0],hw[1],hw[2],hw[3]);
  *(uint4*)(BL + addr) = make_uint4(lw[0],lw[1],lw[2],lw[3]);
}

// ---------------- MFMA GEMM (single): out[n][j] = act( A@W^T + b ) ----------------
template<int K, int ACT>
__global__ __launch_bounds__(256,2) void k_mfgemm(const float* __restrict__ A, const u16* __restrict__ Wg,
                                                  const float* __restrict__ bias, float* __restrict__ out,
                                                  int N){
  constexpr int NKT = K/16;
  __shared__ u16 BH[2*NKT*512];
  __shared__ u16 BL[2*NKT*512];
  const int tid = threadIdx.x;
  const int l = tid & 63;
  const int w = __builtin_amdgcn_readfirstlane(tid >> 6);
  const int rt = w >> 1, nt = w & 1;
  const int nb = blockIdx.x * 64;
  const int hi = l >> 5;

  for (int u = tid; u < 64*(K/8); u += 256){
    int node = u / (K/8);
    int kc = u % (K/8);
    int n = nb + node;
    float v[8];
    if (n < N){
      const float4* s4 = (const float4*)(A + (size_t)n*K + kc*8);
      float4 a = s4[0], b = s4[1];
      v[0]=a.x; v[1]=a.y; v[2]=a.z; v[3]=a.w; v[4]=b.x; v[5]=b.y; v[6]=b.z; v[7]=b.w;
    } else {
      #pragma unroll
      for (int i=0;i<8;++i) v[i]=0.f;
    }
    stageG(v, BH, BL, node, kc, NKT);
  }
  __syncthreads();

  f32x16 acc;
  #pragma unroll
  for (int r=0;r<16;++r) acc[r] = 0.f;
  const u16* wbase = Wg + ((size_t)rt<<10) + ((size_t)l<<3);
  #pragma unroll
  for (int kt = 0; kt < NKT; ++kt){
    const u16* wk = wbase + (size_t)kt*2048;
    short8 Ah = *(const short8*)(wk);
    short8 Al = *(const short8*)(wk + 512);
    int sl = l ^ (((kt<<1) + hi) & 7);
    int baddr = ((nt*NKT + kt)<<9) + (sl<<3);
    short8 Bh = *(const short8*)(BH + baddr);
    short8 Bl = *(const short8*)(BL + baddr);
    acc = __builtin_amdgcn_mfma_f32_32x32x16_bf16(Ah, Bh, acc, 0,0,0);
    acc = __builtin_amdgcn_mfma_f32_32x32x16_bf16(Ah, Bl, acc, 0,0,0);
    acc = __builtin_amdgcn_mfma_f32_32x32x16_bf16(Al, Bh, acc, 0,0,0);
  }

  const int col = l & 31;
  const int n = nb + nt*32 + col;
  if (n < N){
    #pragma unroll
    for (int g = 0; g < 4; ++g){
      const int j0 = rt*32 + 8*g + 4*hi;
      float4 b4 = bias ? *(const float4*)(bias + j0) : make_float4(0.f,0.f,0.f,0.f);
      float4 o;
      o.x = acc[4*g+0] + b4.x;
      o.y = acc[4*g+1] + b4.y;
      o.z = acc[4*g+2] + b4.z;
      o.w = acc[4*g+3] + b4.w;
      if (ACT){
        o.x = fmaxf(o.x, 0.f); o.y = fmaxf(o.y, 0.f);
        o.z = fmaxf(o.z, 0.f); o.w = fmaxf(o.w, 0.f);
      }
      *(float4*)(out + (size_t)n*64 + j0) = o;
    }
  }
}

// ---------------- fused pair: H = relu(Z@Wb+bb) (store) ; Y = H@Wa (store) ----------------
__global__ __launch_bounds__(256,2) void k_mfgemm2(const float* __restrict__ Z, const u16* __restrict__ Wgb,
                                                   const float* __restrict__ bb, const u16* __restrict__ Wga,
                                                   float* __restrict__ Hout, float* __restrict__ Yout,
                                                   int N){
  __shared__ u16 BH[4096];
  __shared__ u16 BL[4096];
  __shared__ float hX[64][68];
  const int tid = threadIdx.x;
  const int l = tid & 63;
  const int w = __builtin_amdgcn_readfirstlane(tid >> 6);
  const int rt = w >> 1, nt = w & 1;
  const int nb = blockIdx.x * 64;
  const int hi = l >> 5;
  const int col = l & 31;
  const int n = nb + nt*32 + col;

  for (int u = tid; u < 512; u += 256){
    int node = u >> 3;
    int kc = u & 7;
    int nn = nb + node;
    float v[8];
    if (nn < N){
      const float4* s4 = (const float4*)(Z + (size_t)nn*64 + kc*8);
      float4 a = s4[0], b = s4[1];
      v[0]=a.x; v[1]=a.y; v[2]=a.z; v[3]=a.w; v[4]=b.x; v[5]=b.y; v[6]=b.z; v[7]=b.w;
    } else {
      #pragma unroll
      for (int i=0;i<8;++i) v[i]=0.f;
    }
    stageG(v, BH, BL, node, kc, 4);
  }
  __syncthreads();

  f32x16 acc;
  #pragma unroll
  for (int r=0;r<16;++r) acc[r] = 0.f;
  {
    const u16* wbase = Wgb + ((size_t)rt<<10) + ((size_t)l<<3);
    #pragma unroll
    for (int kt = 0; kt < 4; ++kt){
      const u16* wk = wbase + (size_t)kt*2048;
      short8 Ah = *(const short8*)(wk);
      short8 Al = *(const short8*)(wk + 512);
      int sl = l ^ (((kt<<1) + hi) & 7);
      int baddr = ((nt*4 + kt)<<9) + (sl<<3);
      short8 Bh = *(const short8*)(BH + baddr);
      short8 Bl = *(const short8*)(BL + baddr);
      acc = __builtin_amdgcn_mfma_f32_32x32x16_bf16(Ah, Bh, acc, 0,0,0);
      acc = __builtin_amdgcn_mfma_f32_32x32x16_bf16(Ah, Bl, acc, 0,0,0);
      acc = __builtin_amdgcn_mfma_f32_32x32x16_bf16(Al, Bh, acc, 0,0,0);
    }
  }
  {
    const int node = nt*32 + col;
    #pragma unroll
    for (int g = 0; g < 4; ++g){
      const int j0 = rt*32 + 8*g + 4*hi;
      float4 b4 = *(const float4*)(bb + j0);
      float4 o;
      o.x = fmaxf(acc[4*g+0] + b4.x, 0.f);
      o.y = fmaxf(acc[4*g+1] + b4.y, 0.f);
      o.z = fmaxf(acc[4*g+2] + b4.z, 0.f);
      o.w = fmaxf(acc[4*g+3] + b4.w, 0.f);
      if (n < N) *(float4*)(Hout + (size_t)n*64 + j0) = o;
      *(float4*)(&hX[node][j0]) = o;
    }
  }
  __syncthreads();

  for (int u = tid; u < 512; u += 256){
    int node = u >> 3;
    int kc = u & 7;
    float v[8];
    #pragma unroll
    for (int i=0;i<8;++i) v[i] = hX[node][kc*8 + i];
    stageG(v, BH, BL, node, kc, 4);
  }
  __syncthreads();

  #pragma unroll
  for (int r=0;r<16;++r) acc[r] = 0.f;
  {
    const u16* wbase = Wga + ((size_t)rt<<10) + ((size_t)l<<3);
    #pragma unroll
    for (int kt = 0; kt < 4; ++kt){
      const u16* wk = wbase + (size_t)kt*2048;
      short8 Ah = *(const short8*)(wk);
      short8 Al = *(const short8*)(wk + 512);
      int sl = l ^ (((kt<<1) + hi) & 7);
      int baddr = ((nt*4 + kt)<<9) + (sl<<3);
      short8 Bh = *(const short8*)(BH + baddr);
      short8 Bl = *(const short8*)(BL + baddr);
      acc = __builtin_amdgcn_mfma_f32_32x32x16_bf16(Ah, Bh, acc, 0,0,0);
      acc = __builtin_amdgcn_mfma_f32_32x32x16_bf16(Ah, Bl, acc, 0,0,0);
      acc = __builtin_amdgcn_mfma_f32_32x32x16_bf16(Al, Bh, acc, 0,0,0);
    }
  }
  if (n < N){
    #pragma unroll
    for (int g = 0; g < 4; ++g){
      const int j0 = rt*32 + 8*g + 4*hi;
      float4 o;
      o.x = acc[4*g+0]; o.y = acc[4*g+1]; o.z = acc[4*g+2]; o.w = acc[4*g+3];
      *(float4*)(Yout + (size_t)n*64 + j0) = o;
    }
  }
}

// ---------------- MFMA LSTM v5d: bf16-only X (no lo planes at all), ~18KB LDS ----------------
// XH [kt(0..9)][slot(64)][8] u16 (x bf16 for kt<4, h bf16 for kt>=4); hFH u16[96][32].
__device__ __forceinline__ void ldx_regs(const float* __restrict__ seq, int blk, int N, int tid,
                                         float (&v)[8]){
  int node = tid >> 3;
  int kc = tid & 7;
  int n = blk*32 + node;
  if (n < N){
    const float4* s4 = (const float4*)(seq + (size_t)n*64 + kc*8);
    float4 a = s4[0], b = s4[1];
    v[0]=a.x; v[1]=a.y; v[2]=a.z; v[3]=a.w; v[4]=b.x; v[5]=b.y; v[6]=b.z; v[7]=b.w;
  } else {
    #pragma unroll
    for (int i=0;i<8;++i) v[i]=0.f;
  }
}

__device__ __forceinline__ void stage_x_h16(const float (&v)[8], u16* __restrict__ XH, int tid){
  int node = tid >> 3;
  int kc = tid & 7;
  u32 hw[4];
  #pragma unroll
  for (int i=0;i<4;++i)
    hw[i] = (u32)f2bf(v[2*i]) | ((u32)f2bf(v[2*i+1])<<16);
  int kt = kc >> 1, hi = kc & 1;
  int sl = (((hi<<5) | node) ^ (kc & 7));
  int addr = (kt<<9) + (sl<<3);
  *(uint4*)(XH + addr) = make_uint4(hw[0],hw[1],hw[2],hw[3]);
}

__device__ __forceinline__ void restage_h16(const u16 (*hFH)[32], u16* __restrict__ XH, int tid){
  int node = tid & 31;
  #pragma unroll
  for (int q = 0; q < 2; ++q){
    int cc = (tid >> 5) + q*8;
    if (cc < 12){
      int kth = cc >> 1, hi = cc & 1;
      int ktG = kth + 4;
      u32 hw[4];
      #pragma unroll
      for (int i=0;i<4;++i){
        u16 a = hFH[cc*8 + 2*i][node];
        u16 b = hFH[cc*8 + 2*i + 1][node];
        hw[i] = (u32)a | ((u32)b<<16);
      }
      int sl = (((hi<<5) | node) ^ ((2*ktG + hi) & 7));
      int addr = (ktG<<9) + (sl<<3);
      *(uint4*)(XH + addr) = make_uint4(hw[0],hw[1],hw[2],hw[3]);
    }
  }
}

template<int FIRST, int WRITEH>
__device__ __forceinline__ float lstm_step5(const u16* __restrict__ Wp,
    const float4* __restrict__ Bp, const float* __restrict__ WattW,
    const u16* __restrict__ XH, u16 (*hFH)[32],
    float (&c)[12], int rtg, int l)
{
  constexpr int NKT = FIRST ? 4 : 10;
  const int hi = l >> 5;
  const int col = l & 31;
  f32x16 acc[3];
  #pragma unroll
  for (int t=0;t<3;++t)
    #pragma unroll
    for (int r=0;r<16;++r) acc[t][r] = 0.f;

  const u16* wbase = Wp + (size_t)(rtg*3)*512 + ((size_t)l<<3);
  #pragma unroll
  for (int kt = 0; kt < NKT; ++kt){
    const u16* wk = wbase + (size_t)kt*6144;
    short8 A0 = *(const short8*)(wk);
    short8 A1 = *(const short8*)(wk + 512);
    short8 A2 = *(const short8*)(wk + 1024);
    int sl = l ^ (((kt<<1) + hi) & 7);
    int baddr = (kt<<9) + (sl<<3);
    short8 Bh = *(const short8*)(XH + baddr);
    __builtin_amdgcn_s_setprio(1);
    acc[0] = __builtin_amdgcn_mfma_f32_32x32x16_bf16(A0, Bh, acc[0], 0,0,0);
    acc[1] = __builtin_amdgcn_mfma_f32_32x32x16_bf16(A1, Bh, acc[1], 0,0,0);
    acc[2] = __builtin_amdgcn_mfma_f32_32x32x16_bf16(A2, Bh, acc[2], 0,0,0);
    __builtin_amdgcn_s_setprio(0);
  }

  float aP = 0.f;
  #pragma unroll
  for (int ti=0;ti<3;++ti){
    #pragma unroll
    for (int rg=0; rg<4; ++rg){
      const int j = (rtg*3+ti)*8 + 2*rg + hi;
      float4 bv = Bp[j];
      float gi = acc[ti][rg*4+0] + bv.x;
      float gf = acc[ti][rg*4+1] + bv.y;
      float gg = acc[ti][rg*4+2] + bv.z;
      float go = acc[ti][rg*4+3] + bv.w;
      const int ci = ti*4 + rg;
      float cp = FIRST ? 0.f : c[ci];
      float cn = sigf(gf)*cp + sigf(gi)*tanh_f(gg);
      float hh = sigf(go)*tanh_f(cn);
      c[ci] = cn;
      aP = fmaf(hh, WattW[j], aP);
      if (WRITEH) hFH[j][col] = f2bf(hh);
    }
  }
  return aP;
}

__global__ __launch_bounds__(256,2) void k_lstm5(
    const float* __restrict__ h1, const float* __restrict__ h2, const float* __restrict__ h3,
    const u16* __restrict__ Wpf, const u16* __restrict__ Wpb,
    const float4* __restrict__ Bpf, const float4* __restrict__ Bpb,
    const float* __restrict__ Watt, const float* __restrict__ batt,
    float* __restrict__ aF, float* __restrict__ aB, int gL, int N)
{
  __shared__ u16 XH[5120];
  __shared__ u16 hFH[96][32];
  __shared__ float sAl[4][3][32];
  const int tid = threadIdx.x;
  const int l = tid & 63;
  const int rtg = __builtin_amdgcn_readfirstlane(tid >> 6);
  const int dir = (blockIdx.x >= gL) ? 1 : 0;
  const int blk = blockIdx.x - dir*gL;
  const float* sA = dir ? h3 : h1;
  const float* sC = dir ? h1 : h3;
  const u16* Wp = dir ? Wpb : Wpf;
  const float4* Bp = dir ? Bpb : Bpf;
  const float* WattW = Watt + dir*96;
  float* aD = dir ? aB : aF;
  float c[12];
  float a0, a1, a2;
  float xv[8];

  ldx_regs(sA, blk, N, tid, xv);
  stage_x_h16(xv, XH, tid);
  ldx_regs(h2, blk, N, tid, xv);
  __syncthreads();

  a0 = lstm_step5<1,1>(Wp, Bp, WattW, XH, hFH, c, rtg, l);
  __syncthreads();
  stage_x_h16(xv, XH, tid);
  restage_h16(hFH, XH, tid);
  ldx_regs(sC, blk, N, tid, xv);
  __syncthreads();

  a1 = lstm_step5<0,1>(Wp, Bp, WattW, XH, hFH, c, rtg, l);
  __syncthreads();
  stage_x_h16(xv, XH, tid);
  restage_h16(hFH, XH, tid);
  __syncthreads();

  a2 = lstm_step5<0,0>(Wp, Bp, WattW, XH, hFH, c, rtg, l);

  a0 += __shfl_xor(a0, 32);
  a1 += __shfl_xor(a1, 32);
  a2 += __shfl_xor(a2, 32);
  if (l < 32){
    sAl[rtg][0][l] = a0;
    sAl[rtg][1][l] = a1;
    sAl[rtg][2][l] = a2;
  }
  __syncthreads();
  if (tid < 96){
    int s = tid >> 5;
    int node = tid & 31;
    int n = blk*32 + node;
    if (n < N){
      float sum = sAl[0][s][node] + sAl[1][s][node]
                + sAl[2][s][node] + sAl[3][s][node];
      int slice = dir ? (2 - s) : s;
      float v = dir ? sum : (batt[0] + sum);
      aD[(size_t)slice*N + n] = v;
    }
  }
}

// ---------------- JK via MFMA: softmax + xjk + Wlin + fc1-dot + leaky ----------------
__global__ __launch_bounds__(256,2) void k_jk2(const float* __restrict__ aF, const float* __restrict__ aB,
                                               const float* __restrict__ h1, const float* __restrict__ h2,
                                               const float* __restrict__ h3,
                                               const u16* __restrict__ WgL, const float* __restrict__ blin,
                                               const float* __restrict__ Wfc1, const float* __restrict__ bfc1,
                                               float* __restrict__ vout, int N){
  __shared__ u16 BH[4096];
  __shared__ u16 BL[4096];
  __shared__ float sP[4][32];
  const int tid = threadIdx.x;
  const int l = tid & 63;
  const int w = __builtin_amdgcn_readfirstlane(tid >> 6);
  const int rt = w >> 1, nt = w & 1;
  const int nb = blockIdx.x * 64;
  const int hi = l >> 5;

  for (int u = tid; u < 512; u += 256){
    int node = u >> 3;
    int kc = u & 7;
    int n = nb + node;
    float v[8];
    if (n < N){
      float a0 = aF[n] + aB[n];
      float a1 = aF[(size_t)N + n] + aB[(size_t)N + n];
      float a2 = aF[(size_t)2*N + n] + aB[(size_t)2*N + n];
      float m = fmaxf(a0, fmaxf(a1, a2));
      float e0 = __expf(a0-m), e1 = __expf(a1-m), e2 = __expf(a2-m);
      float inv = __builtin_amdgcn_rcpf(e0+e1+e2);
      float w0 = e0*inv, w1 = e1*inv, w2 = e2*inv;
      const float4* p1 = (const float4*)(h1 + (size_t)n*64 + kc*8);
      const float4* p2 = (const float4*)(h2 + (size_t)n*64 + kc*8);
      const float4* p3 = (const float4*)(h3 + (size_t)n*64 + kc*8);
      #pragma unroll
      for (int q=0;q<2;++q){
        float4 x1 = p1[q], x2 = p2[q], x3 = p3[q];
        v[4*q+0] = w0*x1.x + w1*x2.x + w2*x3.x;
        v[4*q+1] = w0*x1.y + w1*x2.y + w2*x3.y;
        v[4*q+2] = w0*x1.z + w1*x2.z + w2*x3.z;
        v[4*q+3] = w0*x1.w + w1*x2.w + w2*x3.w;
      }
    } else {
      #pragma unroll
      for (int i=0;i<8;++i) v[i]=0.f;
    }
    stageG(v, BH, BL, node, kc, 4);
  }
  __syncthreads();

  f32x16 acc;
  #pragma unroll
  for (int r=0;r<16;++r) acc[r] = 0.f;
  const u16* wbase = WgL + ((size_t)rt<<10) + ((size_t)l<<3);
  #pragma unroll
  for (int kt = 0; kt < 4; ++kt){
    const u16* wk = wbase + (size_t)kt*2048;
    short8 Ah = *(const short8*)(wk);
    short8 Al = *(const short8*)(wk + 512);
    int sl = l ^ (((kt<<1) + hi) & 7);
    int baddr = ((nt*4 + kt)<<9) + (sl<<3);
    short8 Bh = *(const short8*)(BH + baddr);
    short8 Bl = *(const short8*)(BL + baddr);
    acc = __builtin_amdgcn_mfma_f32_32x32x16_bf16(Ah, Bh, acc, 0,0,0);
    acc = __builtin_amdgcn_mfma_f32_32x32x16_bf16(Ah, Bl, acc, 0,0,0);
    acc = __builtin_amdgcn_mfma_f32_32x32x16_bf16(Al, Bh, acc, 0,0,0);
  }

  float p = 0.f;
  #pragma unroll
  for (int g = 0; g < 4; ++g){
    #pragma unroll
    for (int rg = 0; rg < 4; ++rg){
      const int j = rt*32 + 8*g + 4*hi + rg;
      p += (acc[4*g+rg] + blin[j]) * Wfc1[j];
    }
  }
  p += __shfl_xor(p, 32);
  if (l < 32) sP[w][l] = p;
  __syncthreads();
  if (tid < 64){
    int node = tid;
    int nt2 = node >> 5, c2 = node & 31;
    int n = nb + node;
    if (n < N){
      float t = sP[nt2][c2] + sP[2+nt2][c2] + bfc1[0];
      vout[n] = t >= 0.f ? t : 0.01f*t;
    }
  }
}

// ---------------- final dot (deterministic two-stage, f64 accum) ----------------
__global__ __launch_bounds__(256) void k_final1(const float* __restrict__ w, const float* __restrict__ v,
                                                double* __restrict__ part, int N){
  __shared__ double sd[256];
  int tid = threadIdx.x;
  double a = 0.0;
  for (int i = blockIdx.x*256 + tid; i < N; i += 256*256)
    a += (double)(w[i] * v[i]);
  sd[tid] = a; __syncthreads();
  for (int off = 128; off > 0; off >>= 1){
    if (tid < off) sd[tid] += sd[tid + off];
    __syncthreads();
  }
  if (tid == 0) part[blockIdx.x] = sd[0];
}

__global__ __launch_bounds__(256) void k_final2(const double* __restrict__ part, const float* __restrict__ bfc2,
                                                float* __restrict__ out){
  __shared__ double sd[256];
  int tid = threadIdx.x;
  sd[tid] = part[tid]; __syncthreads();
  for (int off = 128; off > 0; off >>= 1){
    if (tid < off) sd[tid] += sd[tid + off];
    __syncthreads();
  }
  if (tid == 0) out[0] = (float)(sd[0] + (double)bfc2[0]);
}

// ---------------- host ----------------
extern "C" void kernel_launch(void* const* d_in, const int* in_sizes, int n_in,
                              void* d_out, int out_size, void* d_ws, size_t ws_size,
                              hipStream_t stream){
  const float* x    = (const float*)d_in[0];
  const int*   ei   = (const int*)d_in[1];
  const float* W0a  = (const float*)d_in[2];
  const float* b0a  = (const float*)d_in[3];
  const float* W0b  = (const float*)d_in[4];
  const float* b0b  = (const float*)d_in[5];
  const float* W1a  = (const float*)d_in[6];
  const float* b1a  = (const float*)d_in[7];
  const float* W1b  = (const float*)d_in[8];
  const float* b1b  = (const float*)d_in[9];
  const float* W2a  = (const float*)d_in[10];
  const float* b2a  = (const float*)d_in[11];
  const float* W2b  = (const float*)d_in[12];
  const float* b2b  = (const float*)d_in[13];
  const float* Wih_f = (const float*)d_in[14];
  const float* Whh_f = (const float*)d_in[15];
  const float* bih_f = (const float*)d_in[16];
  const float* bhh_f = (const float*)d_in[17];
  const float* Wih_b = (const float*)d_in[18];
  const float* Whh_b = (const float*)d_in[19];
  const float* bih_b = (const float*)d_in[20];
  const float* bhh_b = (const float*)d_in[21];
  const float* Watt = (const float*)d_in[22];
  const float* batt = (const float*)d_in[23];
  const float* Wlin = (const float*)d_in[24];
  const float* blin = (const float*)d_in[25];
  const float* Wfc1 = (const float*)d_in[26];
  const float* bfc1 = (const float*)d_in[27];
  const float* Wfc2 = (const float*)d_in[28];
  const float* bfc2 = (const float*)d_in[29];
  float* out = (float*)d_out;

  const int N = in_sizes[0] / 128;
  const int E = in_sizes[1] / 2;
  const int* src = ei;
  const int* dst = ei + E;

  uint8_t* w8 = (uint8_t*)d_ws;
  size_t off = 0;
  auto alloc = [&](size_t bytes) -> void* {
    void* p = w8 + off;
    off = (off + bytes + 255) & ~(size_t)255;
    return p;
  };
  int*    deg    = (int*)   alloc((size_t)N*4);
  int*    fill   = (int*)   alloc((size_t)N*4);
  int*    indptr = (int*)   alloc(((size_t)N+1)*4);
  int*    col    = (int*)   alloc((size_t)E*4);
  int*    bsum   = (int*)   alloc(2048);
  int*    boffs  = (int*)   alloc(2048);
  float*  h1     = (float*) alloc((size_t)N*64*4);
  float*  h2     = (float*) alloc((size_t)N*64*4);
  float*  h3     = (float*) alloc((size_t)N*64*4);
  float*  aF     = (float*) alloc((size_t)3*N*4);
  float*  aB     = (float*) alloc((size_t)3*N*4);
  float*  vbuf   = (float*) alloc((size_t)N*4);
  double* part   = (double*)alloc(256*8);
  u16*    Wpf    = (u16*)   alloc((size_t)10*12*64*8*2);
  u16*    Wpb    = (u16*)   alloc((size_t)10*12*64*8*2);
  float4* Bpf    = (float4*)alloc((size_t)96*16);
  float4* Bpb    = (float4*)alloc((size_t)96*16);
  u16*    Wg0a   = (u16*)   alloc((size_t)128*128*2);
  u16*    Wg0b   = (u16*)   alloc((size_t)64*128*2);
  u16*    Wg1a   = (u16*)   alloc((size_t)64*128*2);
  u16*    Wg1b   = (u16*)   alloc((size_t)64*128*2);
  u16*    Wg2a   = (u16*)   alloc((size_t)64*128*2);
  u16*    Wg2b   = (u16*)   alloc((size_t)64*128*2);
  u16*    WgL    = (u16*)   alloc((size_t)64*128*2);
  float*  P      = (float*) alloc((size_t)N*192*4);
  if (off > ws_size) return;
  float* ybuf = P;
  float* zbuf = P + (size_t)N*64;

  // one memset covers deg + pad + fill (contiguous allocs)
  size_t zlen = (size_t)((uint8_t*)fill - (uint8_t*)deg) + (size_t)N*4;
  hipMemsetAsync(deg, 0, zlen, stream);

  int gE = (E + 255) / 256;
  int nb1 = (N + 255) / 256;
  int gG = (N + 63) / 64;
  int gA = (N + 15) / 16;
  int gL = (N + 31) / 32;

  // single prepack dispatch
  k_packAll<<<737, 256, 0, stream>>>(Wih_f, Whh_f, Wih_b, Whh_b,
                                     bih_f, bhh_f, bih_b, bhh_b,
                                     W0a, W0b, W1a, W1b, W2a, W2b, Wlin,
                                     Wpf, Wpb, Bpf, Bpb,
                                     Wg0a, Wg0b, Wg1a, Wg1b, Wg2a, Wg2b, WgL);

  k_deg  <<<gE, 256, 0, stream>>>(dst, deg, E);
  k_scan1<<<nb1, 256, 0, stream>>>(deg, indptr, bsum, N);
  k_scan2<<<1, 512, 0, stream>>>(bsum, boffs, indptr, nb1, N);
  k_scan3<<<nb1, 256, 0, stream>>>(indptr, boffs, N);
  k_fill <<<gE, 256, 0, stream>>>(src, dst, indptr, fill, col, E);

  // ---- GIN layer 0 ----
  k_mfgemm<128,0><<<gG, 256, 0, stream>>>(x, Wg0a, nullptr, ybuf, N);
  k_agg<64><<<gA, 256, 0, stream>>>(ybuf, indptr, col, b0a, zbuf, N);
  k_mfgemm2<<<gG, 256, 0, stream>>>(zbuf, Wg0b, b0b, Wg1a, h1, ybuf, N);
  // ---- GIN layer 1 ----
  k_agg<64><<<gA, 256, 0, stream>>>(ybuf, indptr, col, b1a, zbuf, N);
  k_mfgemm2<<<gG, 256, 0, stream>>>(zbuf, Wg1b, b1b, Wg2a, h2, ybuf, N);
  // ---- GIN layer 2 ----
  k_agg<64><<<gA, 256, 0, stream>>>(ybuf, indptr, col, b2a, zbuf, N);
  k_mfgemm<64,1><<<gG, 256, 0, stream>>>(zbuf, Wg2b, b2b, h3, N);

  // ---- LSTM: both directions in one dispatch ----
  k_lstm5<<<2*gL, 256, 0, stream>>>(h1, h2, h3, Wpf, Wpb, Bpf, Bpb, Watt, batt,
                                    aF, aB, gL, N);

  // ---- JK attention + linear + fc1 + leaky (MFMA) ----
  k_jk2<<<gG, 256, 0, stream>>>(aF, aB, h1, h2, h3, WgL, blin, Wfc1, bfc1, vbuf, N);

  // ---- final dot ----
  k_final1<<<256, 256, 0, stream>>>(Wfc2, vbuf, part, N);
  k_final2<<<1, 256, 0, stream>>>(part, bfc2, out);
}